// Round 2
// baseline (859.698 us; speedup 1.0000x reference)
//
#include <hip/hip_runtime.h>

typedef short short8 __attribute__((ext_vector_type(8)));
typedef float f32x4 __attribute__((ext_vector_type(4)));

#define N_NODES  50000
#define N_EDGES  800000
#define HID      128
#define EDGE_D   16
#define N_GRAPHS 64
#define KP1      288   // layer-1 K padded: 128 h_row + 128 h_col + 16 edge_attr + 1 radial + 15 pad

__device__ __forceinline__ unsigned short f2b(float f) {
    union { unsigned int i; float f; } v; v.f = f;
    return (unsigned short)((v.i + 0x7FFFu + ((v.i >> 16) & 1u)) >> 16);
}
__device__ __forceinline__ float silu_f(float x) { return x / (1.0f + __expf(-x)); }

__device__ __forceinline__ short8 cvt8(const float* __restrict__ p) {
    float4 f0 = *(const float4*)p;
    float4 f1 = *(const float4*)(p + 4);
    short8 r;
    r[0] = (short)f2b(f0.x); r[1] = (short)f2b(f0.y);
    r[2] = (short)f2b(f0.z); r[3] = (short)f2b(f0.w);
    r[4] = (short)f2b(f1.x); r[5] = (short)f2b(f1.y);
    r[6] = (short)f2b(f1.z); r[7] = (short)f2b(f1.w);
    return r;
}

// ---------------------------------------------------------------------------
// Prep: fp32 -> bf16 for h and all weights; weights transposed to [N][K]
// (B-operand wants contiguous K per output column). Layer-1 K reordered:
// [h_row 0:128 | h_col 128:256 | edge_attr 256:272 | radial 272 | zeros :288]
// ---------------------------------------------------------------------------
__global__ void prep_kernel(
    const float* __restrict__ We1, const float* __restrict__ We2,
    const float* __restrict__ Wn1, const float* __restrict__ Wn2,
    const float* __restrict__ h,
    unsigned short* __restrict__ We1T, unsigned short* __restrict__ We2T,
    unsigned short* __restrict__ Wn1T, unsigned short* __restrict__ Wn2T,
    unsigned short* __restrict__ h_bf16)
{
    int stride = gridDim.x * blockDim.x;
    int i0 = blockIdx.x * blockDim.x + threadIdx.x;
    for (int t = i0; t < (N_NODES * HID) / 8; t += stride) {
        *(short8*)(h_bf16 + t * 8) = cvt8(h + t * 8);
    }
    for (int t = i0; t < 128 * KP1; t += stride) {
        int n = t / KP1, kp = t % KP1;
        float v = 0.f;
        int k;
        if (kp < 256) k = kp;            // h_row / h_col rows of We1
        else if (kp < 272) k = kp + 1;   // edge_attr rows (orig 257..272)
        else if (kp == 272) k = 256;     // radial row (orig 256)
        else k = -1;                     // zero padding
        if (k >= 0) v = We1[k * HID + n];
        We1T[n * KP1 + kp] = f2b(v);
    }
    for (int t = i0; t < 128 * 128; t += stride) {
        int n = t >> 7, k = t & 127;
        We2T[n * HID + k] = f2b(We2[k * HID + n]);
        Wn2T[n * HID + k] = f2b(Wn2[k * HID + n]);
    }
    for (int t = i0; t < 128 * 256; t += stride) {
        int n = t >> 8, k = t & 255;
        Wn1T[n * 256 + k] = f2b(Wn1[k * HID + n]);
    }
}

// ---------------------------------------------------------------------------
// Edge MLP: per block 64 edges x 128 out, 4 waves (16 edges each).
// A-fragments loaded straight from global bf16 h (A-layout wants 8 contiguous
// k per lane). B chunks staged in LDS. Epilogue scatters silu(layer2) into
// agg[row] with fp32 atomics.
// ---------------------------------------------------------------------------
__global__ __launch_bounds__(256, 2) void edge_kernel(
    const unsigned short* __restrict__ h,      // bf16
    const int* __restrict__ ei,
    const float* __restrict__ x,
    const float* __restrict__ ea,
    const unsigned short* __restrict__ We1T,
    const float* __restrict__ be1,
    const unsigned short* __restrict__ We2T,
    const float* __restrict__ be2,
    float* __restrict__ agg)
{
    __shared__ unsigned short Wc[128 * 40];   // weight chunk [n][kk], pad 32->40
    __shared__ unsigned short efs[64 * 136];  // layer-1 act tile [m][n], pad 128->136
    __shared__ int rowL[64];
    __shared__ int colL[64];
    __shared__ float radF[64];

    const int tid  = threadIdx.x;
    const int wave = tid >> 6;
    const int lane = tid & 63;
    const int quad = lane >> 4;
    const int l16  = lane & 15;
    const int e0   = blockIdx.x * 64;

    if (tid < 64) {
        int e = e0 + tid;
        int r = ei[e];
        int c = ei[N_EDGES + e];
        r = min(max(r, 0), N_NODES - 1);
        c = min(max(c, 0), N_NODES - 1);
        rowL[tid] = r;
        colL[tid] = c;
        float dx = x[r * 3 + 0] - x[c * 3 + 0];
        float dy = x[r * 3 + 1] - x[c * 3 + 1];
        float dz = x[r * 3 + 2] - x[c * 3 + 2];
        radF[tid] = dx * dx + dy * dy + dz * dz;
    }
    __syncthreads();

    const int rA = rowL[wave * 16 + l16];
    const int cA = colL[wave * 16 + l16];
    const int eA = e0 + wave * 16 + l16;

    const f32x4 fz = {0.f, 0.f, 0.f, 0.f};
    f32x4 acc[8];
#pragma unroll
    for (int i = 0; i < 8; ++i) acc[i] = fz;

    // ---- layer 1: K = 288 ----
    for (int kt = 0; kt < 9; ++kt) {
        __syncthreads();
#pragma unroll
        for (int it = 0; it < 2; ++it) {
            int idx = tid + it * 256;            // 512 x 16B = 8KB chunk
            int n = idx >> 2, part = idx & 3;
            *(short8*)(Wc + n * 40 + part * 8) =
                *(const short8*)(We1T + n * KP1 + kt * 32 + part * 8);
        }
        short8 a;
        if (kt < 4) {
            a = *(const short8*)(h + rA * HID + kt * 32 + quad * 8);
        } else if (kt < 8) {
            a = *(const short8*)(h + cA * HID + (kt - 4) * 32 + quad * 8);
        } else {
            short8 t = {0, 0, 0, 0, 0, 0, 0, 0};
            if (quad == 0)      t = cvt8(ea + eA * EDGE_D);
            else if (quad == 1) t = cvt8(ea + eA * EDGE_D + 8);
            else if (quad == 2) t[0] = (short)f2b(radF[wave * 16 + l16]);
            a = t;
        }
        __syncthreads();
#pragma unroll
        for (int nt = 0; nt < 8; ++nt) {
            short8 b = *(const short8*)(Wc + (nt * 16 + l16) * 40 + quad * 8);
            acc[nt] = __builtin_amdgcn_mfma_f32_16x16x32_bf16(a, b, acc[nt], 0, 0, 0);
        }
    }

    // layer-1 epilogue: bias + silu -> efs (bf16)
#pragma unroll
    for (int nt = 0; nt < 8; ++nt) {
        float bias = be1[nt * 16 + l16];
#pragma unroll
        for (int r = 0; r < 4; ++r) {
            int m = wave * 16 + quad * 4 + r;
            efs[m * 136 + nt * 16 + l16] = f2b(silu_f(acc[nt][r] + bias));
        }
        acc[nt] = fz;
    }

    // ---- layer 2: K = 128 ----
    for (int kt = 0; kt < 4; ++kt) {
        __syncthreads();
#pragma unroll
        for (int it = 0; it < 2; ++it) {
            int idx = tid + it * 256;
            int n = idx >> 2, part = idx & 3;
            *(short8*)(Wc + n * 40 + part * 8) =
                *(const short8*)(We2T + n * HID + kt * 32 + part * 8);
        }
        __syncthreads();
        short8 a = *(const short8*)(efs + (wave * 16 + l16) * 136 + kt * 32 + quad * 8);
#pragma unroll
        for (int nt = 0; nt < 8; ++nt) {
            short8 b = *(const short8*)(Wc + (nt * 16 + l16) * 40 + quad * 8);
            acc[nt] = __builtin_amdgcn_mfma_f32_16x16x32_bf16(a, b, acc[nt], 0, 0, 0);
        }
    }

    // layer-2 epilogue: bias + silu + scatter-add to agg[row]
    float bias2[8];
#pragma unroll
    for (int nt = 0; nt < 8; ++nt) bias2[nt] = be2[nt * 16 + l16];
#pragma unroll
    for (int r = 0; r < 4; ++r) {
        int rr = rowL[wave * 16 + quad * 4 + r];
#pragma unroll
        for (int nt = 0; nt < 8; ++nt) {
            float v = silu_f(acc[nt][r] + bias2[nt]);
            atomicAdd(&agg[rr * HID + nt * 16 + l16], v);
        }
    }
}

// ---------------------------------------------------------------------------
// Node MLP + residual + fused pooled-sum scatter. 64 nodes/block.
// K = 256: first half from h (bf16), second half from agg (fp32 -> bf16).
// ---------------------------------------------------------------------------
__global__ __launch_bounds__(256, 2) void node_kernel(
    const unsigned short* __restrict__ hb,     // bf16 h
    const float* __restrict__ hf,              // fp32 h (residual)
    const float* __restrict__ agg,
    const int* __restrict__ batch,
    const unsigned short* __restrict__ Wn1T,
    const float* __restrict__ bn1,
    const unsigned short* __restrict__ Wn2T,
    const float* __restrict__ bn2,
    float* __restrict__ sums)
{
    __shared__ unsigned short Wc[128 * 40];
    __shared__ unsigned short efs[64 * 136];
    __shared__ int batchL[64];

    const int tid  = threadIdx.x;
    const int wave = tid >> 6;
    const int lane = tid & 63;
    const int quad = lane >> 4;
    const int l16  = lane & 15;
    const int n0   = blockIdx.x * 64;

    if (tid < 64) {
        int nd = n0 + tid;
        int g = (nd < N_NODES) ? batch[nd] : 0;
        batchL[tid] = min(max(g, 0), N_GRAPHS - 1);
    }

    const int ndA = min(n0 + wave * 16 + l16, N_NODES - 1);

    const f32x4 fz = {0.f, 0.f, 0.f, 0.f};
    f32x4 acc[8];
#pragma unroll
    for (int i = 0; i < 8; ++i) acc[i] = fz;

    // ---- layer 1: K = 256 ----
    for (int kt = 0; kt < 8; ++kt) {
        __syncthreads();
#pragma unroll
        for (int it = 0; it < 2; ++it) {
            int idx = tid + it * 256;
            int n = idx >> 2, part = idx & 3;
            *(short8*)(Wc + n * 40 + part * 8) =
                *(const short8*)(Wn1T + n * 256 + kt * 32 + part * 8);
        }
        short8 a;
        if (kt < 4) {
            a = *(const short8*)(hb + ndA * HID + kt * 32 + quad * 8);
        } else {
            a = cvt8(agg + ndA * HID + (kt - 4) * 32 + quad * 8);
        }
        __syncthreads();
#pragma unroll
        for (int nt = 0; nt < 8; ++nt) {
            short8 b = *(const short8*)(Wc + (nt * 16 + l16) * 40 + quad * 8);
            acc[nt] = __builtin_amdgcn_mfma_f32_16x16x32_bf16(a, b, acc[nt], 0, 0, 0);
        }
    }

#pragma unroll
    for (int nt = 0; nt < 8; ++nt) {
        float bias = bn1[nt * 16 + l16];
#pragma unroll
        for (int r = 0; r < 4; ++r) {
            int m = wave * 16 + quad * 4 + r;
            efs[m * 136 + nt * 16 + l16] = f2b(silu_f(acc[nt][r] + bias));
        }
        acc[nt] = fz;
    }

    // ---- layer 2: K = 128 (linear, no activation) ----
    for (int kt = 0; kt < 4; ++kt) {
        __syncthreads();
#pragma unroll
        for (int it = 0; it < 2; ++it) {
            int idx = tid + it * 256;
            int n = idx >> 2, part = idx & 3;
            *(short8*)(Wc + n * 40 + part * 8) =
                *(const short8*)(Wn2T + n * HID + kt * 32 + part * 8);
        }
        __syncthreads();
        short8 a = *(const short8*)(efs + (wave * 16 + l16) * 136 + kt * 32 + quad * 8);
#pragma unroll
        for (int nt = 0; nt < 8; ++nt) {
            short8 b = *(const short8*)(Wc + (nt * 16 + l16) * 40 + quad * 8);
            acc[nt] = __builtin_amdgcn_mfma_f32_16x16x32_bf16(a, b, acc[nt], 0, 0, 0);
        }
    }

    // epilogue: bias + residual + pooled-sum scatter
    float bias2[8];
#pragma unroll
    for (int nt = 0; nt < 8; ++nt) bias2[nt] = bn2[nt * 16 + l16];
#pragma unroll
    for (int r = 0; r < 4; ++r) {
        int mloc = wave * 16 + quad * 4 + r;
        int ndM = n0 + mloc;
        if (ndM < N_NODES) {
            int g = batchL[mloc];
#pragma unroll
            for (int nt = 0; nt < 8; ++nt) {
                int nn = nt * 16 + l16;
                float outv = acc[nt][r] + bias2[nt];
                float hn = hf[ndM * HID + nn] + outv;
                atomicAdd(&sums[g * HID + nn], hn);
            }
        }
    }
}

__global__ void count_kernel(const int* __restrict__ batch, int* __restrict__ cnt) {
    int i = blockIdx.x * blockDim.x + threadIdx.x;
    if (i < N_NODES) {
        int g = min(max(batch[i], 0), N_GRAPHS - 1);
        atomicAdd(&cnt[g], 1);
    }
}

__global__ void final_kernel(const float* __restrict__ sums, const int* __restrict__ cnt,
                             float* __restrict__ out) {
    int i = blockIdx.x * blockDim.x + threadIdx.x;
    if (i < N_GRAPHS * HID) {
        float c = (float)cnt[i >> 7];
        c = fmaxf(c, 1.0f);
        out[i] = sums[i] / c;
    }
}

extern "C" void kernel_launch(void* const* d_in, const int* in_sizes, int n_in,
                              void* d_out, int out_size, void* d_ws, size_t ws_size,
                              hipStream_t stream)
{
    const float* h   = (const float*)d_in[0];
    const int*   ei  = (const int*)d_in[1];
    const float* x   = (const float*)d_in[2];
    const float* ea  = (const float*)d_in[3];
    const int*   bat = (const int*)d_in[4];
    const float* We1 = (const float*)d_in[5];
    const float* be1 = (const float*)d_in[6];
    const float* We2 = (const float*)d_in[7];
    const float* be2 = (const float*)d_in[8];
    const float* Wn1 = (const float*)d_in[9];
    const float* bn1 = (const float*)d_in[10];
    const float* Wn2 = (const float*)d_in[11];
    const float* bn2 = (const float*)d_in[12];

    char* ws = (char*)d_ws;
    unsigned short* We1T = (unsigned short*)(ws + 0);         // 73,728 B
    unsigned short* We2T = (unsigned short*)(ws + 73728);     // 32,768 B
    unsigned short* Wn1T = (unsigned short*)(ws + 106496);    // 65,536 B
    unsigned short* Wn2T = (unsigned short*)(ws + 172032);    // 32,768 B
    float*          sums = (float*)(ws + 204800);             // 32,768 B
    int*            cnt  = (int*)(ws + 237568);               // 256 B
    float*          agg  = (float*)(ws + 237824);             // 25,600,000 B
    unsigned short* hb   = (unsigned short*)(ws + 25837824);  // 12,800,000 B -> end 38,637,824

    // zero sums + cnt + agg in one shot (contiguous)
    hipMemsetAsync(ws + 204800, 0, 33024 + 25600000, stream);

    prep_kernel<<<512, 256, 0, stream>>>(We1, We2, Wn1, Wn2, h, We1T, We2T, Wn1T, Wn2T, hb);
    count_kernel<<<(N_NODES + 255) / 256, 256, 0, stream>>>(bat, cnt);
    edge_kernel<<<N_EDGES / 64, 256, 0, stream>>>(hb, ei, x, ea, We1T, be1, We2T, be2, agg);
    node_kernel<<<(N_NODES + 63) / 64, 256, 0, stream>>>(hb, h, agg, bat, Wn1T, bn1, Wn2T, bn2, sums);
    final_kernel<<<(N_GRAPHS * HID + 255) / 256, 256, 0, stream>>>(sums, cnt, (float*)d_out);
}

// Round 3
// 821.532 us; speedup vs baseline: 1.0465x; 1.0465x over previous
//
#include <hip/hip_runtime.h>

typedef short short8 __attribute__((ext_vector_type(8)));
typedef float f32x4 __attribute__((ext_vector_type(4)));

#define N_NODES  50000
#define N_EDGES  800000
#define HID      128
#define EDGE_D   16
#define N_GRAPHS 64
#define KP1      288   // layer-1 K padded: 128 h_row + 128 h_col + 16 edge_attr + 1 radial + 15 pad

__device__ __forceinline__ unsigned short f2b(float f) {
    union { unsigned int i; float f; } v; v.f = f;
    return (unsigned short)((v.i + 0x7FFFu + ((v.i >> 16) & 1u)) >> 16);
}
__device__ __forceinline__ float silu_f(float x) { return x / (1.0f + __expf(-x)); }

__device__ __forceinline__ short8 cvt8(const float* __restrict__ p) {
    float4 f0 = *(const float4*)p;
    float4 f1 = *(const float4*)(p + 4);
    short8 r;
    r[0] = (short)f2b(f0.x); r[1] = (short)f2b(f0.y);
    r[2] = (short)f2b(f0.z); r[3] = (short)f2b(f0.w);
    r[4] = (short)f2b(f1.x); r[5] = (short)f2b(f1.y);
    r[6] = (short)f2b(f1.z); r[7] = (short)f2b(f1.w);
    return r;
}

// ---------------------------------------------------------------------------
// Prep: fp32 -> bf16 for h and all weights (transposed to [N][K]); fused
// per-graph node count. Layer-1 K reorder: [h_row | h_col | edge_attr | radial | pad]
// ---------------------------------------------------------------------------
__global__ void prep_kernel(
    const float* __restrict__ We1, const float* __restrict__ We2,
    const float* __restrict__ Wn1, const float* __restrict__ Wn2,
    const float* __restrict__ h, const int* __restrict__ batch,
    unsigned short* __restrict__ We1T, unsigned short* __restrict__ We2T,
    unsigned short* __restrict__ Wn1T, unsigned short* __restrict__ Wn2T,
    unsigned short* __restrict__ h_bf16, int* __restrict__ cnt)
{
    int stride = gridDim.x * blockDim.x;
    int i0 = blockIdx.x * blockDim.x + threadIdx.x;
    for (int t = i0; t < (N_NODES * HID) / 8; t += stride) {
        *(short8*)(h_bf16 + t * 8) = cvt8(h + t * 8);
    }
    for (int t = i0; t < N_NODES; t += stride) {
        int g = min(max(batch[t], 0), N_GRAPHS - 1);
        atomicAdd(&cnt[g], 1);
    }
    for (int t = i0; t < 128 * KP1; t += stride) {
        int n = t / KP1, kp = t % KP1;
        float v = 0.f;
        int k;
        if (kp < 256) k = kp;
        else if (kp < 272) k = kp + 1;
        else if (kp == 272) k = 256;
        else k = -1;
        if (k >= 0) v = We1[k * HID + n];
        We1T[n * KP1 + kp] = f2b(v);
    }
    for (int t = i0; t < 128 * 128; t += stride) {
        int n = t >> 7, k = t & 127;
        We2T[n * HID + k] = f2b(We2[k * HID + n]);
        Wn2T[n * HID + k] = f2b(Wn2[k * HID + n]);
    }
    for (int t = i0; t < 128 * 256; t += stride) {
        int n = t >> 8, k = t & 255;
        Wn1T[n * 256 + k] = f2b(Wn1[k * HID + n]);
    }
}

// ---------------------------------------------------------------------------
// Edge MLP: 512 threads, 256 edges/block, each wave owns 32 edges (2 m-tiles).
// Weight chunk in LDS layout [part(quad)][n][8] -> one b128 per (n,quad), each
// B-read feeds 2 MFMAs. One-step 8KB staging (512 x 16B). 2 barriers per kt.
// ---------------------------------------------------------------------------
__global__ __launch_bounds__(512, 4) void edge_kernel(
    const unsigned short* __restrict__ h,      // bf16
    const int* __restrict__ ei,
    const float* __restrict__ x,
    const float* __restrict__ ea,
    const unsigned short* __restrict__ We1T,
    const float* __restrict__ be1,
    const unsigned short* __restrict__ We2T,
    const float* __restrict__ be2,
    float* __restrict__ agg)
{
    __shared__ unsigned short efs[256 * 136];       // 69,632 B
    __shared__ unsigned short Wc[4 * 128 * 8];      //  8,192 B  [part][n][8]
    __shared__ unsigned short rowS[256];            //    512 B
    __shared__ unsigned short colS[256];            //    512 B
    __shared__ float radF[256];                     //  1,024 B  -> 79,872 total

    const int tid  = threadIdx.x;
    const int wave = tid >> 6;
    const int lane = tid & 63;
    const int quad = lane >> 4;
    const int l16  = lane & 15;
    const int e0   = blockIdx.x * 256;

    if (tid < 256) {
        int e = e0 + tid;
        int r = ei[e];
        int c = ei[N_EDGES + e];
        r = min(max(r, 0), N_NODES - 1);
        c = min(max(c, 0), N_NODES - 1);
        rowS[tid] = (unsigned short)r;
        colS[tid] = (unsigned short)c;
        float dx = x[r * 3 + 0] - x[c * 3 + 0];
        float dy = x[r * 3 + 1] - x[c * 3 + 1];
        float dz = x[r * 3 + 2] - x[c * 3 + 2];
        radF[tid] = dx * dx + dy * dy + dz * dz;
    }
    __syncthreads();

    const int m0 = wave * 32 + l16;      // local edge idx, tile 0
    const int m1 = m0 + 16;              // tile 1
    const int rA0 = rowS[m0], cA0 = colS[m0];
    const int rA1 = rowS[m1], cA1 = colS[m1];
    const int eA0 = e0 + m0, eA1 = e0 + m1;

    const int stg_n = tid >> 2, stg_p = tid & 3;    // staging: n 0..127, part 0..3
    unsigned short* stg_dst = Wc + stg_p * 1024 + stg_n * 8;

    const f32x4 fz = {0.f, 0.f, 0.f, 0.f};
    f32x4 acc0[8], acc1[8];
#pragma unroll
    for (int i = 0; i < 8; ++i) { acc0[i] = fz; acc1[i] = fz; }

    // ---- layer 1: K = 288 ----
    for (int kt = 0; kt < 9; ++kt) {
        __syncthreads();
        *(short8*)stg_dst = *(const short8*)(We1T + stg_n * KP1 + kt * 32 + stg_p * 8);
        short8 a0, a1;
        if (kt < 4) {
            a0 = *(const short8*)(h + rA0 * HID + kt * 32 + quad * 8);
            a1 = *(const short8*)(h + rA1 * HID + kt * 32 + quad * 8);
        } else if (kt < 8) {
            a0 = *(const short8*)(h + cA0 * HID + (kt - 4) * 32 + quad * 8);
            a1 = *(const short8*)(h + cA1 * HID + (kt - 4) * 32 + quad * 8);
        } else {
            short8 t0 = {0, 0, 0, 0, 0, 0, 0, 0}, t1 = t0;
            if (quad == 0)      { t0 = cvt8(ea + eA0 * EDGE_D);     t1 = cvt8(ea + eA1 * EDGE_D); }
            else if (quad == 1) { t0 = cvt8(ea + eA0 * EDGE_D + 8); t1 = cvt8(ea + eA1 * EDGE_D + 8); }
            else if (quad == 2) { t0[0] = (short)f2b(radF[m0]);     t1[0] = (short)f2b(radF[m1]); }
            a0 = t0; a1 = t1;
        }
        __syncthreads();
#pragma unroll
        for (int nt = 0; nt < 8; ++nt) {
            short8 b = *(const short8*)(Wc + quad * 1024 + (nt * 16 + l16) * 8);
            acc0[nt] = __builtin_amdgcn_mfma_f32_16x16x32_bf16(a0, b, acc0[nt], 0, 0, 0);
            acc1[nt] = __builtin_amdgcn_mfma_f32_16x16x32_bf16(a1, b, acc1[nt], 0, 0, 0);
        }
    }

    // layer-1 epilogue: bias + silu -> efs (bf16), both m-tiles
#pragma unroll
    for (int nt = 0; nt < 8; ++nt) {
        float bias = be1[nt * 16 + l16];
#pragma unroll
        for (int r = 0; r < 4; ++r) {
            int mm = wave * 32 + quad * 4 + r;
            efs[mm * 136 + nt * 16 + l16]        = f2b(silu_f(acc0[nt][r] + bias));
            efs[(mm + 16) * 136 + nt * 16 + l16] = f2b(silu_f(acc1[nt][r] + bias));
        }
        acc0[nt] = fz; acc1[nt] = fz;
    }

    // ---- layer 2: K = 128 ----
    for (int kt = 0; kt < 4; ++kt) {
        __syncthreads();
        *(short8*)stg_dst = *(const short8*)(We2T + stg_n * HID + kt * 32 + stg_p * 8);
        __syncthreads();
        short8 a0 = *(const short8*)(efs + m0 * 136 + kt * 32 + quad * 8);
        short8 a1 = *(const short8*)(efs + m1 * 136 + kt * 32 + quad * 8);
#pragma unroll
        for (int nt = 0; nt < 8; ++nt) {
            short8 b = *(const short8*)(Wc + quad * 1024 + (nt * 16 + l16) * 8);
            acc0[nt] = __builtin_amdgcn_mfma_f32_16x16x32_bf16(a0, b, acc0[nt], 0, 0, 0);
            acc1[nt] = __builtin_amdgcn_mfma_f32_16x16x32_bf16(a1, b, acc1[nt], 0, 0, 0);
        }
    }

    // layer-2 epilogue: bias + silu + scatter-add to agg[row], both tiles
    float bias2[8];
#pragma unroll
    for (int nt = 0; nt < 8; ++nt) bias2[nt] = be2[nt * 16 + l16];
#pragma unroll
    for (int r = 0; r < 4; ++r) {
        int rr0 = rowS[wave * 32 + quad * 4 + r];
        int rr1 = rowS[wave * 32 + 16 + quad * 4 + r];
#pragma unroll
        for (int nt = 0; nt < 8; ++nt) {
            atomicAdd(&agg[rr0 * HID + nt * 16 + l16], silu_f(acc0[nt][r] + bias2[nt]));
            atomicAdd(&agg[rr1 * HID + nt * 16 + l16], silu_f(acc1[nt][r] + bias2[nt]));
        }
    }
}

// ---------------------------------------------------------------------------
// Node MLP + residual + fused pooled-sum scatter. 512 threads, 128 nodes/block.
// Same staging skeleton. Pool atomics combined across the 4 C-rows when they
// share a graph (batch is sorted -> almost always).
// ---------------------------------------------------------------------------
__global__ __launch_bounds__(512, 4) void node_kernel(
    const unsigned short* __restrict__ hb,     // bf16 h
    const float* __restrict__ hf,              // fp32 h (residual)
    const float* __restrict__ agg,
    const int* __restrict__ batch,
    const unsigned short* __restrict__ Wn1T,
    const float* __restrict__ bn1,
    const unsigned short* __restrict__ Wn2T,
    const float* __restrict__ bn2,
    float* __restrict__ sums)
{
    __shared__ unsigned short efs[128 * 136];   // 34,816 B
    __shared__ unsigned short Wc[4 * 128 * 8];  //  8,192 B
    __shared__ int batchL[128];                 //    512 B

    const int tid  = threadIdx.x;
    const int wave = tid >> 6;
    const int lane = tid & 63;
    const int quad = lane >> 4;
    const int l16  = lane & 15;
    const int n0   = blockIdx.x * 128;

    if (tid < 128) {
        int nd = n0 + tid;
        int g = (nd < N_NODES) ? batch[nd] : 0;
        batchL[tid] = min(max(g, 0), N_GRAPHS - 1);
    }
    __syncthreads();

    const int mA  = wave * 16 + l16;
    const int ndA = min(n0 + mA, N_NODES - 1);
    const int stg_n = tid >> 2, stg_p = tid & 3;
    unsigned short* stg_dst = Wc + stg_p * 1024 + stg_n * 8;

    const f32x4 fz = {0.f, 0.f, 0.f, 0.f};
    f32x4 acc[8];
#pragma unroll
    for (int i = 0; i < 8; ++i) acc[i] = fz;

    // ---- layer 1: K = 256 ----
    for (int kt = 0; kt < 8; ++kt) {
        __syncthreads();
        *(short8*)stg_dst = *(const short8*)(Wn1T + stg_n * 256 + kt * 32 + stg_p * 8);
        short8 a;
        if (kt < 4) a = *(const short8*)(hb + ndA * HID + kt * 32 + quad * 8);
        else        a = cvt8(agg + ndA * HID + (kt - 4) * 32 + quad * 8);
        __syncthreads();
#pragma unroll
        for (int nt = 0; nt < 8; ++nt) {
            short8 b = *(const short8*)(Wc + quad * 1024 + (nt * 16 + l16) * 8);
            acc[nt] = __builtin_amdgcn_mfma_f32_16x16x32_bf16(a, b, acc[nt], 0, 0, 0);
        }
    }

#pragma unroll
    for (int nt = 0; nt < 8; ++nt) {
        float bias = bn1[nt * 16 + l16];
#pragma unroll
        for (int r = 0; r < 4; ++r) {
            int mm = wave * 16 + quad * 4 + r;
            efs[mm * 136 + nt * 16 + l16] = f2b(silu_f(acc[nt][r] + bias));
        }
        acc[nt] = fz;
    }

    // ---- layer 2: K = 128 (linear) ----
    for (int kt = 0; kt < 4; ++kt) {
        __syncthreads();
        *(short8*)stg_dst = *(const short8*)(Wn2T + stg_n * HID + kt * 32 + stg_p * 8);
        __syncthreads();
        short8 a = *(const short8*)(efs + mA * 136 + kt * 32 + quad * 8);
#pragma unroll
        for (int nt = 0; nt < 8; ++nt) {
            short8 b = *(const short8*)(Wc + quad * 1024 + (nt * 16 + l16) * 8);
            acc[nt] = __builtin_amdgcn_mfma_f32_16x16x32_bf16(a, b, acc[nt], 0, 0, 0);
        }
    }

    // epilogue: bias + residual + pooled-sum scatter (graph-combined)
    const int mbase = wave * 16 + quad * 4;
    const int gfirst = batchL[mbase], glast = batchL[min(mbase + 3, 127)];
    const bool same_g = (gfirst == glast) && (n0 + mbase + 3 < N_NODES);
#pragma unroll
    for (int nt = 0; nt < 8; ++nt) {
        int nn = nt * 16 + l16;
        float bias = bn2[nn];
        if (same_g) {
            float s = 0.f;
#pragma unroll
            for (int r = 0; r < 4; ++r) {
                int ndM = n0 + mbase + r;
                s += acc[nt][r] + bias + hf[ndM * HID + nn];
            }
            atomicAdd(&sums[gfirst * HID + nn], s);
        } else {
#pragma unroll
            for (int r = 0; r < 4; ++r) {
                int ndM = n0 + mbase + r;
                if (ndM < N_NODES) {
                    float hn = hf[ndM * HID + nn] + acc[nt][r] + bias;
                    atomicAdd(&sums[batchL[mbase + r] * HID + nn], hn);
                }
            }
        }
    }
}

__global__ void final_kernel(const float* __restrict__ sums, const int* __restrict__ cnt,
                             float* __restrict__ out) {
    int i = blockIdx.x * blockDim.x + threadIdx.x;
    if (i < N_GRAPHS * HID) {
        float c = (float)cnt[i >> 7];
        c = fmaxf(c, 1.0f);
        out[i] = sums[i] / c;
    }
}

extern "C" void kernel_launch(void* const* d_in, const int* in_sizes, int n_in,
                              void* d_out, int out_size, void* d_ws, size_t ws_size,
                              hipStream_t stream)
{
    const float* h   = (const float*)d_in[0];
    const int*   ei  = (const int*)d_in[1];
    const float* x   = (const float*)d_in[2];
    const float* ea  = (const float*)d_in[3];
    const int*   bat = (const int*)d_in[4];
    const float* We1 = (const float*)d_in[5];
    const float* be1 = (const float*)d_in[6];
    const float* We2 = (const float*)d_in[7];
    const float* be2 = (const float*)d_in[8];
    const float* Wn1 = (const float*)d_in[9];
    const float* bn1 = (const float*)d_in[10];
    const float* Wn2 = (const float*)d_in[11];
    const float* bn2 = (const float*)d_in[12];

    char* ws = (char*)d_ws;
    unsigned short* We1T = (unsigned short*)(ws + 0);         // 73,728 B
    unsigned short* We2T = (unsigned short*)(ws + 73728);     // 32,768 B
    unsigned short* Wn1T = (unsigned short*)(ws + 106496);    // 65,536 B
    unsigned short* Wn2T = (unsigned short*)(ws + 172032);    // 32,768 B
    float*          sums = (float*)(ws + 204800);             // 32,768 B
    int*            cnt  = (int*)(ws + 237568);               // 256 B
    float*          agg  = (float*)(ws + 237824);             // 25,600,000 B
    unsigned short* hb   = (unsigned short*)(ws + 25837824);  // 12,800,000 B -> end 38,637,824

    // zero sums + cnt + agg in one shot (contiguous)
    hipMemsetAsync(ws + 204800, 0, 33024 + 25600000, stream);

    prep_kernel<<<512, 256, 0, stream>>>(We1, We2, Wn1, Wn2, h, bat,
                                         We1T, We2T, Wn1T, Wn2T, hb, cnt);
    edge_kernel<<<N_EDGES / 256, 512, 0, stream>>>(hb, ei, x, ea, We1T, be1, We2T, be2, agg);
    node_kernel<<<(N_NODES + 127) / 128, 512, 0, stream>>>(hb, h, agg, bat, Wn1T, bn1, Wn2T, bn2, sums);
    final_kernel<<<(N_GRAPHS * HID + 255) / 256, 256, 0, stream>>>(sums, cnt, (float*)d_out);
}

// Round 4
// 673.399 us; speedup vs baseline: 1.2767x; 1.2200x over previous
//
#include <hip/hip_runtime.h>

typedef short short8 __attribute__((ext_vector_type(8)));
typedef float f32x4 __attribute__((ext_vector_type(4)));

#define N_NODES  50000
#define N_EDGES  800000
#define HID      128
#define EDGE_D   16
#define N_GRAPHS 64
#define KP1      288   // layer-1 K padded: 128 h_row + 128 h_col + 16 edge_attr + 1 radial + 15 pad

__device__ __forceinline__ float b2f(unsigned short u) {
    union { unsigned int i; float f; } v; v.i = ((unsigned int)u) << 16; return v.f;
}
__device__ __forceinline__ unsigned short f2b(float f) {
    union { unsigned int i; float f; } v; v.f = f;
    return (unsigned short)((v.i + 0x7FFFu + ((v.i >> 16) & 1u)) >> 16);
}
__device__ __forceinline__ float silu_f(float x) { return x / (1.0f + __expf(-x)); }

__device__ __forceinline__ short8 cvt8(const float* __restrict__ p) {
    float4 f0 = *(const float4*)p;
    float4 f1 = *(const float4*)(p + 4);
    short8 r;
    r[0] = (short)f2b(f0.x); r[1] = (short)f2b(f0.y);
    r[2] = (short)f2b(f0.z); r[3] = (short)f2b(f0.w);
    r[4] = (short)f2b(f1.x); r[5] = (short)f2b(f1.y);
    r[6] = (short)f2b(f1.z); r[7] = (short)f2b(f1.w);
    return r;
}

// ---------------------------------------------------------------------------
// Prep: fp32->bf16 h + weights (transposed [N][K]); per-graph count; row histogram.
// ---------------------------------------------------------------------------
__global__ void prep_kernel(
    const float* __restrict__ We1, const float* __restrict__ We2,
    const float* __restrict__ Wn1, const float* __restrict__ Wn2,
    const float* __restrict__ h, const int* __restrict__ batch,
    const int* __restrict__ ei,
    unsigned short* __restrict__ We1T, unsigned short* __restrict__ We2T,
    unsigned short* __restrict__ Wn1T, unsigned short* __restrict__ Wn2T,
    unsigned short* __restrict__ h_bf16, int* __restrict__ cnt,
    int* __restrict__ hist)
{
    int stride = gridDim.x * blockDim.x;
    int i0 = blockIdx.x * blockDim.x + threadIdx.x;
    for (int t = i0; t < (N_NODES * HID) / 8; t += stride) {
        *(short8*)(h_bf16 + t * 8) = cvt8(h + t * 8);
    }
    for (int t = i0; t < N_NODES; t += stride) {
        int g = min(max(batch[t], 0), N_GRAPHS - 1);
        atomicAdd(&cnt[g], 1);
    }
    for (int t = i0; t < N_EDGES; t += stride) {
        int r = min(max(ei[t], 0), N_NODES - 1);
        atomicAdd(&hist[r], 1);
    }
    for (int t = i0; t < 128 * KP1; t += stride) {
        int n = t / KP1, kp = t % KP1;
        float v = 0.f;
        int k;
        if (kp < 256) k = kp;
        else if (kp < 272) k = kp + 1;
        else if (kp == 272) k = 256;
        else k = -1;
        if (k >= 0) v = We1[k * HID + n];
        We1T[n * KP1 + kp] = f2b(v);
    }
    for (int t = i0; t < 128 * 128; t += stride) {
        int n = t >> 7, k = t & 127;
        We2T[n * HID + k] = f2b(We2[k * HID + n]);
        Wn2T[n * HID + k] = f2b(Wn2[k * HID + n]);
    }
    for (int t = i0; t < 128 * 256; t += stride) {
        int n = t >> 8, k = t & 255;
        Wn1T[n * 256 + k] = f2b(Wn1[k * HID + n]);
    }
}

// ---------------------------------------------------------------------------
// Two-level exclusive scan of the 50k row histogram (for counting sort).
// ---------------------------------------------------------------------------
__global__ void scan1_kernel(const int* __restrict__ hist, int* __restrict__ offs_local,
                             int* __restrict__ chunk_sums)
{
    __shared__ int buf[256];
    int tid = threadIdx.x, i = blockIdx.x * 256 + tid;
    int v = (i < N_NODES) ? hist[i] : 0;
    buf[tid] = v; __syncthreads();
    for (int off = 1; off < 256; off <<= 1) {
        int t = (tid >= off) ? buf[tid - off] : 0;
        __syncthreads();
        buf[tid] += t;
        __syncthreads();
    }
    if (i < N_NODES) offs_local[i] = buf[tid] - v;
    if (tid == 255) chunk_sums[blockIdx.x] = buf[255];
}

__global__ void scan2_kernel(const int* __restrict__ chunk_sums, int* __restrict__ blockpref)
{
    __shared__ int buf[256];
    int tid = threadIdx.x;
    int v = (tid < 196) ? chunk_sums[tid] : 0;
    buf[tid] = v; __syncthreads();
    for (int off = 1; off < 256; off <<= 1) {
        int t = (tid >= off) ? buf[tid - off] : 0;
        __syncthreads();
        buf[tid] += t;
        __syncthreads();
    }
    if (tid < 196) blockpref[tid] = buf[tid] - v;
}

__global__ void scatter_kernel(const int* __restrict__ ei,
                               const int* __restrict__ offs_local,
                               const int* __restrict__ blockpref,
                               int* __restrict__ cursor,
                               unsigned short* __restrict__ srow,
                               unsigned short* __restrict__ scol,
                               int* __restrict__ seid)
{
    int e = blockIdx.x * 256 + threadIdx.x;
    if (e < N_EDGES) {
        int r = min(max(ei[e], 0), N_NODES - 1);
        int c = min(max(ei[N_EDGES + e], 0), N_NODES - 1);
        int pos = blockpref[r >> 8] + offs_local[r] + atomicAdd(&cursor[r], 1);
        srow[pos] = (unsigned short)r;
        scol[pos] = (unsigned short)c;
        seid[pos] = e;
    }
}

// ---------------------------------------------------------------------------
// Edge MLP over ROW-SORTED edges: 512 thr, 256 edges/block, 2 m-tiles/wave.
// Epilogue: silu -> LDS tile, block segmented-reduce over equal-row runs,
// plain stores to agg for interior rows, atomics only at block boundaries.
// ---------------------------------------------------------------------------
__global__ __launch_bounds__(512, 4) void edge_kernel(
    const unsigned short* __restrict__ h,      // bf16
    const unsigned short* __restrict__ srow,
    const unsigned short* __restrict__ scol,
    const int* __restrict__ seid,
    const float* __restrict__ x,
    const float* __restrict__ ea,
    const unsigned short* __restrict__ We1T,
    const float* __restrict__ be1,
    const unsigned short* __restrict__ We2T,
    const float* __restrict__ be2,
    float* __restrict__ agg)
{
    __shared__ unsigned short efs[256 * 136];       // 69,632 B
    __shared__ unsigned short Wc[4 * 128 * 8];      //  8,192 B  [part][n][8]
    __shared__ unsigned short rowS[256];
    __shared__ unsigned short colS[256];
    __shared__ unsigned short radB[256];
    __shared__ unsigned short segS[256];
    __shared__ unsigned short segL[256];
    __shared__ int nsegL;

    const int tid  = threadIdx.x;
    const int wave = tid >> 6;
    const int lane = tid & 63;
    const int quad = lane >> 4;
    const int l16  = lane & 15;
    const int e0   = blockIdx.x * 256;

    if (tid == 0) nsegL = 0;
    if (tid < 256) {
        int e = e0 + tid;
        int r = srow[e];
        int c = scol[e];
        rowS[tid] = (unsigned short)r;
        colS[tid] = (unsigned short)c;
        float dx = x[r * 3 + 0] - x[c * 3 + 0];
        float dy = x[r * 3 + 1] - x[c * 3 + 1];
        float dz = x[r * 3 + 2] - x[c * 3 + 2];
        radB[tid] = f2b(dx * dx + dy * dy + dz * dz);
    }
    __syncthreads();

    // discover equal-row segments (sorted -> contiguous runs)
    if (tid < 256) {
        bool head = (tid == 0) || (rowS[tid] != rowS[tid - 1]);
        if (head) {
            int j = tid + 1;
            while (j < 256 && rowS[j] == rowS[tid]) ++j;
            int s = atomicAdd(&nsegL, 1);
            segS[s] = (unsigned short)tid;
            segL[s] = (unsigned short)(j - tid);
        }
    }

    const int m0 = wave * 32 + l16;
    const int m1 = m0 + 16;
    const int rA0 = rowS[m0], cA0 = colS[m0];
    const int rA1 = rowS[m1], cA1 = colS[m1];

    const int stg_n = tid >> 2, stg_p = tid & 3;
    unsigned short* stg_dst = Wc + stg_p * 1024 + stg_n * 8;

    const f32x4 fz = {0.f, 0.f, 0.f, 0.f};
    f32x4 acc0[8], acc1[8];
#pragma unroll
    for (int i = 0; i < 8; ++i) { acc0[i] = fz; acc1[i] = fz; }

    // ---- layer 1: K = 288 ----
    for (int kt = 0; kt < 9; ++kt) {
        __syncthreads();
        *(short8*)stg_dst = *(const short8*)(We1T + stg_n * KP1 + kt * 32 + stg_p * 8);
        short8 a0, a1;
        if (kt < 4) {
            a0 = *(const short8*)(h + rA0 * HID + kt * 32 + quad * 8);
            a1 = *(const short8*)(h + rA1 * HID + kt * 32 + quad * 8);
        } else if (kt < 8) {
            a0 = *(const short8*)(h + cA0 * HID + (kt - 4) * 32 + quad * 8);
            a1 = *(const short8*)(h + cA1 * HID + (kt - 4) * 32 + quad * 8);
        } else {
            short8 t0 = {0, 0, 0, 0, 0, 0, 0, 0}, t1 = t0;
            if (quad == 0) {
                t0 = cvt8(ea + (long)seid[e0 + m0] * EDGE_D);
                t1 = cvt8(ea + (long)seid[e0 + m1] * EDGE_D);
            } else if (quad == 1) {
                t0 = cvt8(ea + (long)seid[e0 + m0] * EDGE_D + 8);
                t1 = cvt8(ea + (long)seid[e0 + m1] * EDGE_D + 8);
            } else if (quad == 2) {
                t0[0] = (short)radB[m0];
                t1[0] = (short)radB[m1];
            }
            a0 = t0; a1 = t1;
        }
        __syncthreads();
#pragma unroll
        for (int nt = 0; nt < 8; ++nt) {
            short8 b = *(const short8*)(Wc + quad * 1024 + (nt * 16 + l16) * 8);
            acc0[nt] = __builtin_amdgcn_mfma_f32_16x16x32_bf16(a0, b, acc0[nt], 0, 0, 0);
            acc1[nt] = __builtin_amdgcn_mfma_f32_16x16x32_bf16(a1, b, acc1[nt], 0, 0, 0);
        }
    }

    // layer-1 epilogue: bias + silu -> efs (bf16)
#pragma unroll
    for (int nt = 0; nt < 8; ++nt) {
        float bias = be1[nt * 16 + l16];
#pragma unroll
        for (int r = 0; r < 4; ++r) {
            int mm = wave * 32 + quad * 4 + r;
            efs[mm * 136 + nt * 16 + l16]        = f2b(silu_f(acc0[nt][r] + bias));
            efs[(mm + 16) * 136 + nt * 16 + l16] = f2b(silu_f(acc1[nt][r] + bias));
        }
        acc0[nt] = fz; acc1[nt] = fz;
    }

    // ---- layer 2: K = 128 ----
    for (int kt = 0; kt < 4; ++kt) {
        __syncthreads();
        *(short8*)stg_dst = *(const short8*)(We2T + stg_n * HID + kt * 32 + stg_p * 8);
        __syncthreads();
        short8 a0 = *(const short8*)(efs + m0 * 136 + kt * 32 + quad * 8);
        short8 a1 = *(const short8*)(efs + m1 * 136 + kt * 32 + quad * 8);
#pragma unroll
        for (int nt = 0; nt < 8; ++nt) {
            short8 b = *(const short8*)(Wc + quad * 1024 + (nt * 16 + l16) * 8);
            acc0[nt] = __builtin_amdgcn_mfma_f32_16x16x32_bf16(a0, b, acc0[nt], 0, 0, 0);
            acc1[nt] = __builtin_amdgcn_mfma_f32_16x16x32_bf16(a1, b, acc1[nt], 0, 0, 0);
        }
    }

    // layer-2 epilogue: silu -> efs (own wave's rows; reads of efs done above)
#pragma unroll
    for (int nt = 0; nt < 8; ++nt) {
        float bias = be2[nt * 16 + l16];
#pragma unroll
        for (int r = 0; r < 4; ++r) {
            int mm = wave * 32 + quad * 4 + r;
            efs[mm * 136 + nt * 16 + l16]        = f2b(silu_f(acc0[nt][r] + bias));
            efs[(mm + 16) * 136 + nt * 16 + l16] = f2b(silu_f(acc1[nt][r] + bias));
        }
    }
    __syncthreads();

    // segmented reduce: one store (or boundary atomic) per distinct row
    const int c = tid & 127;
    const int sg = tid >> 7;           // 4 segment groups
    for (int s = sg; s < nsegL; s += 4) {
        int st = segS[s], ln = segL[s];
        int row = rowS[st];
        float sum = 0.f;
        for (int i = 0; i < ln; ++i) sum += b2f(efs[(st + i) * 136 + c]);
        if (st == 0 || st + ln == 256) atomicAdd(&agg[row * HID + c], sum);
        else                           agg[row * HID + c] = sum;
    }
}

// ---------------------------------------------------------------------------
// Node MLP + residual + fused pooled-sum scatter (unchanged from round 3).
// ---------------------------------------------------------------------------
__global__ __launch_bounds__(512, 4) void node_kernel(
    const unsigned short* __restrict__ hb,
    const float* __restrict__ hf,
    const float* __restrict__ agg,
    const int* __restrict__ batch,
    const unsigned short* __restrict__ Wn1T,
    const float* __restrict__ bn1,
    const unsigned short* __restrict__ Wn2T,
    const float* __restrict__ bn2,
    float* __restrict__ sums)
{
    __shared__ unsigned short efs[128 * 136];
    __shared__ unsigned short Wc[4 * 128 * 8];
    __shared__ int batchL[128];

    const int tid  = threadIdx.x;
    const int wave = tid >> 6;
    const int lane = tid & 63;
    const int quad = lane >> 4;
    const int l16  = lane & 15;
    const int n0   = blockIdx.x * 128;

    if (tid < 128) {
        int nd = n0 + tid;
        int g = (nd < N_NODES) ? batch[nd] : 0;
        batchL[tid] = min(max(g, 0), N_GRAPHS - 1);
    }
    __syncthreads();

    const int mA  = wave * 16 + l16;
    const int ndA = min(n0 + mA, N_NODES - 1);
    const int stg_n = tid >> 2, stg_p = tid & 3;
    unsigned short* stg_dst = Wc + stg_p * 1024 + stg_n * 8;

    const f32x4 fz = {0.f, 0.f, 0.f, 0.f};
    f32x4 acc[8];
#pragma unroll
    for (int i = 0; i < 8; ++i) acc[i] = fz;

    for (int kt = 0; kt < 8; ++kt) {
        __syncthreads();
        *(short8*)stg_dst = *(const short8*)(Wn1T + stg_n * 256 + kt * 32 + stg_p * 8);
        short8 a;
        if (kt < 4) a = *(const short8*)(hb + ndA * HID + kt * 32 + quad * 8);
        else        a = cvt8(agg + ndA * HID + (kt - 4) * 32 + quad * 8);
        __syncthreads();
#pragma unroll
        for (int nt = 0; nt < 8; ++nt) {
            short8 b = *(const short8*)(Wc + quad * 1024 + (nt * 16 + l16) * 8);
            acc[nt] = __builtin_amdgcn_mfma_f32_16x16x32_bf16(a, b, acc[nt], 0, 0, 0);
        }
    }

#pragma unroll
    for (int nt = 0; nt < 8; ++nt) {
        float bias = bn1[nt * 16 + l16];
#pragma unroll
        for (int r = 0; r < 4; ++r) {
            int mm = wave * 16 + quad * 4 + r;
            efs[mm * 136 + nt * 16 + l16] = f2b(silu_f(acc[nt][r] + bias));
        }
        acc[nt] = fz;
    }

    for (int kt = 0; kt < 4; ++kt) {
        __syncthreads();
        *(short8*)stg_dst = *(const short8*)(Wn2T + stg_n * HID + kt * 32 + stg_p * 8);
        __syncthreads();
        short8 a = *(const short8*)(efs + mA * 136 + kt * 32 + quad * 8);
#pragma unroll
        for (int nt = 0; nt < 8; ++nt) {
            short8 b = *(const short8*)(Wc + quad * 1024 + (nt * 16 + l16) * 8);
            acc[nt] = __builtin_amdgcn_mfma_f32_16x16x32_bf16(a, b, acc[nt], 0, 0, 0);
        }
    }

    const int mbase = wave * 16 + quad * 4;
    const int gfirst = batchL[mbase], glast = batchL[min(mbase + 3, 127)];
    const bool same_g = (gfirst == glast) && (n0 + mbase + 3 < N_NODES);
#pragma unroll
    for (int nt = 0; nt < 8; ++nt) {
        int nn = nt * 16 + l16;
        float bias = bn2[nn];
        if (same_g) {
            float s = 0.f;
#pragma unroll
            for (int r = 0; r < 4; ++r) {
                int ndM = n0 + mbase + r;
                s += acc[nt][r] + bias + hf[ndM * HID + nn];
            }
            atomicAdd(&sums[gfirst * HID + nn], s);
        } else {
#pragma unroll
            for (int r = 0; r < 4; ++r) {
                int ndM = n0 + mbase + r;
                if (ndM < N_NODES) {
                    float hn = hf[ndM * HID + nn] + acc[nt][r] + bias;
                    atomicAdd(&sums[batchL[mbase + r] * HID + nn], hn);
                }
            }
        }
    }
}

__global__ void final_kernel(const float* __restrict__ sums, const int* __restrict__ cnt,
                             float* __restrict__ out) {
    int i = blockIdx.x * blockDim.x + threadIdx.x;
    if (i < N_GRAPHS * HID) {
        float c = (float)cnt[i >> 7];
        c = fmaxf(c, 1.0f);
        out[i] = sums[i] / c;
    }
}

extern "C" void kernel_launch(void* const* d_in, const int* in_sizes, int n_in,
                              void* d_out, int out_size, void* d_ws, size_t ws_size,
                              hipStream_t stream)
{
    const float* h   = (const float*)d_in[0];
    const int*   ei  = (const int*)d_in[1];
    const float* x   = (const float*)d_in[2];
    const float* ea  = (const float*)d_in[3];
    const int*   bat = (const int*)d_in[4];
    const float* We1 = (const float*)d_in[5];
    const float* be1 = (const float*)d_in[6];
    const float* We2 = (const float*)d_in[7];
    const float* be2 = (const float*)d_in[8];
    const float* Wn1 = (const float*)d_in[9];
    const float* bn1 = (const float*)d_in[10];
    const float* Wn2 = (const float*)d_in[11];
    const float* bn2 = (const float*)d_in[12];

    char* ws = (char*)d_ws;
    unsigned short* We1T = (unsigned short*)(ws + 0);          //    73,728
    unsigned short* We2T = (unsigned short*)(ws + 73728);      //    32,768
    unsigned short* Wn1T = (unsigned short*)(ws + 106496);     //    65,536
    unsigned short* Wn2T = (unsigned short*)(ws + 172032);     //    32,768
    int*   offs_local    = (int*)(ws + 204800);                //   200,000
    int*   chunk_sums    = (int*)(ws + 404800);                //     1,024
    int*   blockpref     = (int*)(ws + 405824);                //     1,024
    unsigned short* srow = (unsigned short*)(ws + 406848);     // 1,600,000
    unsigned short* scol = (unsigned short*)(ws + 2006848);    // 1,600,000
    int*   seid          = (int*)(ws + 3606848);               // 3,200,000
    unsigned short* hb   = (unsigned short*)(ws + 6806848);    // 12,800,000
    // ---- zeroed region (contiguous) ----
    float* sums          = (float*)(ws + 19606848);            //    32,768
    int*   cnt           = (int*)(ws + 19639616);              //       256
    int*   hist          = (int*)(ws + 19639872);              //   200,000
    int*   cursor        = (int*)(ws + 19839872);              //   200,000
    float* agg           = (float*)(ws + 20039872);            // 25,600,000 -> end 45,639,872

    hipMemsetAsync(ws + 19606848, 0, 26033024, stream);

    prep_kernel<<<512, 256, 0, stream>>>(We1, We2, Wn1, Wn2, h, bat, ei,
                                         We1T, We2T, Wn1T, Wn2T, hb, cnt, hist);
    scan1_kernel<<<196, 256, 0, stream>>>(hist, offs_local, chunk_sums);
    scan2_kernel<<<1, 256, 0, stream>>>(chunk_sums, blockpref);
    scatter_kernel<<<(N_EDGES + 255) / 256, 256, 0, stream>>>(ei, offs_local, blockpref,
                                                              cursor, srow, scol, seid);
    edge_kernel<<<N_EDGES / 256, 512, 0, stream>>>(hb, srow, scol, seid, x, ea,
                                                   We1T, be1, We2T, be2, agg);
    node_kernel<<<(N_NODES + 127) / 128, 512, 0, stream>>>(hb, h, agg, bat,
                                                           Wn1T, bn1, Wn2T, bn2, sums);
    final_kernel<<<(N_GRAPHS * HID + 255) / 256, 256, 0, stream>>>(sums, cnt, (float*)d_out);
}

// Round 5
// 498.823 us; speedup vs baseline: 1.7235x; 1.3500x over previous
//
#include <hip/hip_runtime.h>

typedef short short8 __attribute__((ext_vector_type(8)));
typedef float f32x4 __attribute__((ext_vector_type(4)));

#define N_NODES  50000
#define N_EDGES  800000
#define HID      128
#define EDGE_D   16
#define N_GRAPHS 64
#define KP1      288   // layer-1 K padded: 128 h_row + 128 h_col + 16 edge_attr + 1 radial + 15 pad

__device__ __forceinline__ float b2f(unsigned short u) {
    union { unsigned int i; float f; } v; v.i = ((unsigned int)u) << 16; return v.f;
}
__device__ __forceinline__ unsigned short f2b(float f) {
    union { unsigned int i; float f; } v; v.f = f;
    return (unsigned short)((v.i + 0x7FFFu + ((v.i >> 16) & 1u)) >> 16);
}
__device__ __forceinline__ float silu_f(float x) { return x / (1.0f + __expf(-x)); }

__device__ __forceinline__ short8 cvt8(const float* __restrict__ p) {
    float4 f0 = *(const float4*)p;
    float4 f1 = *(const float4*)(p + 4);
    short8 r;
    r[0] = (short)f2b(f0.x); r[1] = (short)f2b(f0.y);
    r[2] = (short)f2b(f0.z); r[3] = (short)f2b(f0.w);
    r[4] = (short)f2b(f1.x); r[5] = (short)f2b(f1.y);
    r[6] = (short)f2b(f1.z); r[7] = (short)f2b(f1.w);
    return r;
}

// ---------------------------------------------------------------------------
// Prep: fp32->bf16 h + weights (transposed [N][K]); row histogram for sort.
// NOTE: no per-graph count here — 50k same-address atomics on a 256B array
// serialized at L2 (~200us, round-4 counters); counts are now computed by
// binary search over the sorted batch in final_kernel.
// ---------------------------------------------------------------------------
__global__ void prep_kernel(
    const float* __restrict__ We1, const float* __restrict__ We2,
    const float* __restrict__ Wn1, const float* __restrict__ Wn2,
    const float* __restrict__ h,
    const int* __restrict__ ei,
    unsigned short* __restrict__ We1T, unsigned short* __restrict__ We2T,
    unsigned short* __restrict__ Wn1T, unsigned short* __restrict__ Wn2T,
    unsigned short* __restrict__ h_bf16,
    int* __restrict__ hist)
{
    int stride = gridDim.x * blockDim.x;
    int i0 = blockIdx.x * blockDim.x + threadIdx.x;
    for (int t = i0; t < (N_NODES * HID) / 8; t += stride) {
        *(short8*)(h_bf16 + t * 8) = cvt8(h + t * 8);
    }
    for (int t = i0; t < N_EDGES; t += stride) {
        int r = min(max(ei[t], 0), N_NODES - 1);
        atomicAdd(&hist[r], 1);
    }
    for (int t = i0; t < 128 * KP1; t += stride) {
        int n = t / KP1, kp = t % KP1;
        float v = 0.f;
        int k;
        if (kp < 256) k = kp;
        else if (kp < 272) k = kp + 1;
        else if (kp == 272) k = 256;
        else k = -1;
        if (k >= 0) v = We1[k * HID + n];
        We1T[n * KP1 + kp] = f2b(v);
    }
    for (int t = i0; t < 128 * 128; t += stride) {
        int n = t >> 7, k = t & 127;
        We2T[n * HID + k] = f2b(We2[k * HID + n]);
        Wn2T[n * HID + k] = f2b(Wn2[k * HID + n]);
    }
    for (int t = i0; t < 128 * 256; t += stride) {
        int n = t >> 8, k = t & 255;
        Wn1T[n * 256 + k] = f2b(Wn1[k * HID + n]);
    }
}

// ---------------------------------------------------------------------------
// Two-level exclusive scan of the 50k row histogram (for counting sort).
// ---------------------------------------------------------------------------
__global__ void scan1_kernel(const int* __restrict__ hist, int* __restrict__ offs_local,
                             int* __restrict__ chunk_sums)
{
    __shared__ int buf[256];
    int tid = threadIdx.x, i = blockIdx.x * 256 + tid;
    int v = (i < N_NODES) ? hist[i] : 0;
    buf[tid] = v; __syncthreads();
    for (int off = 1; off < 256; off <<= 1) {
        int t = (tid >= off) ? buf[tid - off] : 0;
        __syncthreads();
        buf[tid] += t;
        __syncthreads();
    }
    if (i < N_NODES) offs_local[i] = buf[tid] - v;
    if (tid == 255) chunk_sums[blockIdx.x] = buf[255];
}

__global__ void scan2_kernel(const int* __restrict__ chunk_sums, int* __restrict__ blockpref)
{
    __shared__ int buf[256];
    int tid = threadIdx.x;
    int v = (tid < 196) ? chunk_sums[tid] : 0;
    buf[tid] = v; __syncthreads();
    for (int off = 1; off < 256; off <<= 1) {
        int t = (tid >= off) ? buf[tid - off] : 0;
        __syncthreads();
        buf[tid] += t;
        __syncthreads();
    }
    if (tid < 196) blockpref[tid] = buf[tid] - v;
}

__global__ void scatter_kernel(const int* __restrict__ ei,
                               const int* __restrict__ offs_local,
                               const int* __restrict__ blockpref,
                               int* __restrict__ cursor,
                               unsigned short* __restrict__ srow,
                               unsigned short* __restrict__ scol,
                               int* __restrict__ seid)
{
    int e = blockIdx.x * 256 + threadIdx.x;
    if (e < N_EDGES) {
        int r = min(max(ei[e], 0), N_NODES - 1);
        int c = min(max(ei[N_EDGES + e], 0), N_NODES - 1);
        int pos = blockpref[r >> 8] + offs_local[r] + atomicAdd(&cursor[r], 1);
        srow[pos] = (unsigned short)r;
        scol[pos] = (unsigned short)c;
        seid[pos] = e;
    }
}

// ---------------------------------------------------------------------------
// Edge MLP over ROW-SORTED edges: 512 thr, 256 edges/block, 2 m-tiles/wave.
// Epilogue: silu -> LDS tile, block segmented-reduce over equal-row runs,
// plain stores to agg for interior rows, atomics only at block boundaries.
// ---------------------------------------------------------------------------
__global__ __launch_bounds__(512, 4) void edge_kernel(
    const unsigned short* __restrict__ h,      // bf16
    const unsigned short* __restrict__ srow,
    const unsigned short* __restrict__ scol,
    const int* __restrict__ seid,
    const float* __restrict__ x,
    const float* __restrict__ ea,
    const unsigned short* __restrict__ We1T,
    const float* __restrict__ be1,
    const unsigned short* __restrict__ We2T,
    const float* __restrict__ be2,
    float* __restrict__ agg)
{
    __shared__ unsigned short efs[256 * 136];       // 69,632 B
    __shared__ unsigned short Wc[4 * 128 * 8];      //  8,192 B  [part][n][8]
    __shared__ unsigned short rowS[256];
    __shared__ unsigned short colS[256];
    __shared__ unsigned short radB[256];
    __shared__ unsigned short segS[256];
    __shared__ unsigned short segL[256];
    __shared__ int nsegL;

    const int tid  = threadIdx.x;
    const int wave = tid >> 6;
    const int lane = tid & 63;
    const int quad = lane >> 4;
    const int l16  = lane & 15;
    const int e0   = blockIdx.x * 256;

    if (tid == 0) nsegL = 0;
    if (tid < 256) {
        int e = e0 + tid;
        int r = srow[e];
        int c = scol[e];
        rowS[tid] = (unsigned short)r;
        colS[tid] = (unsigned short)c;
        float dx = x[r * 3 + 0] - x[c * 3 + 0];
        float dy = x[r * 3 + 1] - x[c * 3 + 1];
        float dz = x[r * 3 + 2] - x[c * 3 + 2];
        radB[tid] = f2b(dx * dx + dy * dy + dz * dz);
    }
    __syncthreads();

    // discover equal-row segments (sorted -> contiguous runs)
    if (tid < 256) {
        bool head = (tid == 0) || (rowS[tid] != rowS[tid - 1]);
        if (head) {
            int j = tid + 1;
            while (j < 256 && rowS[j] == rowS[tid]) ++j;
            int s = atomicAdd(&nsegL, 1);
            segS[s] = (unsigned short)tid;
            segL[s] = (unsigned short)(j - tid);
        }
    }

    const int m0 = wave * 32 + l16;
    const int m1 = m0 + 16;
    const int rA0 = rowS[m0], cA0 = colS[m0];
    const int rA1 = rowS[m1], cA1 = colS[m1];

    const int stg_n = tid >> 2, stg_p = tid & 3;
    unsigned short* stg_dst = Wc + stg_p * 1024 + stg_n * 8;

    const f32x4 fz = {0.f, 0.f, 0.f, 0.f};
    f32x4 acc0[8], acc1[8];
#pragma unroll
    for (int i = 0; i < 8; ++i) { acc0[i] = fz; acc1[i] = fz; }

    // ---- layer 1: K = 288 ----
    for (int kt = 0; kt < 9; ++kt) {
        __syncthreads();
        *(short8*)stg_dst = *(const short8*)(We1T + stg_n * KP1 + kt * 32 + stg_p * 8);
        short8 a0, a1;
        if (kt < 4) {
            a0 = *(const short8*)(h + rA0 * HID + kt * 32 + quad * 8);
            a1 = *(const short8*)(h + rA1 * HID + kt * 32 + quad * 8);
        } else if (kt < 8) {
            a0 = *(const short8*)(h + cA0 * HID + (kt - 4) * 32 + quad * 8);
            a1 = *(const short8*)(h + cA1 * HID + (kt - 4) * 32 + quad * 8);
        } else {
            short8 t0 = {0, 0, 0, 0, 0, 0, 0, 0}, t1 = t0;
            if (quad == 0) {
                t0 = cvt8(ea + (long)seid[e0 + m0] * EDGE_D);
                t1 = cvt8(ea + (long)seid[e0 + m1] * EDGE_D);
            } else if (quad == 1) {
                t0 = cvt8(ea + (long)seid[e0 + m0] * EDGE_D + 8);
                t1 = cvt8(ea + (long)seid[e0 + m1] * EDGE_D + 8);
            } else if (quad == 2) {
                t0[0] = (short)radB[m0];
                t1[0] = (short)radB[m1];
            }
            a0 = t0; a1 = t1;
        }
        __syncthreads();
#pragma unroll
        for (int nt = 0; nt < 8; ++nt) {
            short8 b = *(const short8*)(Wc + quad * 1024 + (nt * 16 + l16) * 8);
            acc0[nt] = __builtin_amdgcn_mfma_f32_16x16x32_bf16(a0, b, acc0[nt], 0, 0, 0);
            acc1[nt] = __builtin_amdgcn_mfma_f32_16x16x32_bf16(a1, b, acc1[nt], 0, 0, 0);
        }
    }

    // layer-1 epilogue: bias + silu -> efs (bf16)
#pragma unroll
    for (int nt = 0; nt < 8; ++nt) {
        float bias = be1[nt * 16 + l16];
#pragma unroll
        for (int r = 0; r < 4; ++r) {
            int mm = wave * 32 + quad * 4 + r;
            efs[mm * 136 + nt * 16 + l16]        = f2b(silu_f(acc0[nt][r] + bias));
            efs[(mm + 16) * 136 + nt * 16 + l16] = f2b(silu_f(acc1[nt][r] + bias));
        }
        acc0[nt] = fz; acc1[nt] = fz;
    }

    // ---- layer 2: K = 128 ----
    for (int kt = 0; kt < 4; ++kt) {
        __syncthreads();
        *(short8*)stg_dst = *(const short8*)(We2T + stg_n * HID + kt * 32 + stg_p * 8);
        __syncthreads();
        short8 a0 = *(const short8*)(efs + m0 * 136 + kt * 32 + quad * 8);
        short8 a1 = *(const short8*)(efs + m1 * 136 + kt * 32 + quad * 8);
#pragma unroll
        for (int nt = 0; nt < 8; ++nt) {
            short8 b = *(const short8*)(Wc + quad * 1024 + (nt * 16 + l16) * 8);
            acc0[nt] = __builtin_amdgcn_mfma_f32_16x16x32_bf16(a0, b, acc0[nt], 0, 0, 0);
            acc1[nt] = __builtin_amdgcn_mfma_f32_16x16x32_bf16(a1, b, acc1[nt], 0, 0, 0);
        }
    }

    // layer-2 epilogue: silu -> efs (own wave's rows; reads of efs done above)
#pragma unroll
    for (int nt = 0; nt < 8; ++nt) {
        float bias = be2[nt * 16 + l16];
#pragma unroll
        for (int r = 0; r < 4; ++r) {
            int mm = wave * 32 + quad * 4 + r;
            efs[mm * 136 + nt * 16 + l16]        = f2b(silu_f(acc0[nt][r] + bias));
            efs[(mm + 16) * 136 + nt * 16 + l16] = f2b(silu_f(acc1[nt][r] + bias));
        }
    }
    __syncthreads();

    // segmented reduce: one store (or boundary atomic) per distinct row
    const int c = tid & 127;
    const int sg = tid >> 7;           // 4 segment groups
    for (int s = sg; s < nsegL; s += 4) {
        int st = segS[s], ln = segL[s];
        int row = rowS[st];
        float sum = 0.f;
        for (int i = 0; i < ln; ++i) sum += b2f(efs[(st + i) * 136 + c]);
        if (st == 0 || st + ln == 256) atomicAdd(&agg[row * HID + c], sum);
        else                           agg[row * HID + c] = sum;
    }
}

// ---------------------------------------------------------------------------
// Node MLP + residual + fused pooled-sum scatter.
// ---------------------------------------------------------------------------
__global__ __launch_bounds__(512, 4) void node_kernel(
    const unsigned short* __restrict__ hb,
    const float* __restrict__ hf,
    const float* __restrict__ agg,
    const int* __restrict__ batch,
    const unsigned short* __restrict__ Wn1T,
    const float* __restrict__ bn1,
    const unsigned short* __restrict__ Wn2T,
    const float* __restrict__ bn2,
    float* __restrict__ sums)
{
    __shared__ unsigned short efs[128 * 136];
    __shared__ unsigned short Wc[4 * 128 * 8];
    __shared__ int batchL[128];

    const int tid  = threadIdx.x;
    const int wave = tid >> 6;
    const int lane = tid & 63;
    const int quad = lane >> 4;
    const int l16  = lane & 15;
    const int n0   = blockIdx.x * 128;

    if (tid < 128) {
        int nd = n0 + tid;
        int g = (nd < N_NODES) ? batch[nd] : 0;
        batchL[tid] = min(max(g, 0), N_GRAPHS - 1);
    }
    __syncthreads();

    const int mA  = wave * 16 + l16;
    const int ndA = min(n0 + mA, N_NODES - 1);
    const int stg_n = tid >> 2, stg_p = tid & 3;
    unsigned short* stg_dst = Wc + stg_p * 1024 + stg_n * 8;

    const f32x4 fz = {0.f, 0.f, 0.f, 0.f};
    f32x4 acc[8];
#pragma unroll
    for (int i = 0; i < 8; ++i) acc[i] = fz;

    for (int kt = 0; kt < 8; ++kt) {
        __syncthreads();
        *(short8*)stg_dst = *(const short8*)(Wn1T + stg_n * 256 + kt * 32 + stg_p * 8);
        short8 a;
        if (kt < 4) a = *(const short8*)(hb + ndA * HID + kt * 32 + quad * 8);
        else        a = cvt8(agg + ndA * HID + (kt - 4) * 32 + quad * 8);
        __syncthreads();
#pragma unroll
        for (int nt = 0; nt < 8; ++nt) {
            short8 b = *(const short8*)(Wc + quad * 1024 + (nt * 16 + l16) * 8);
            acc[nt] = __builtin_amdgcn_mfma_f32_16x16x32_bf16(a, b, acc[nt], 0, 0, 0);
        }
    }

#pragma unroll
    for (int nt = 0; nt < 8; ++nt) {
        float bias = bn1[nt * 16 + l16];
#pragma unroll
        for (int r = 0; r < 4; ++r) {
            int mm = wave * 16 + quad * 4 + r;
            efs[mm * 136 + nt * 16 + l16] = f2b(silu_f(acc[nt][r] + bias));
        }
        acc[nt] = fz;
    }

    for (int kt = 0; kt < 4; ++kt) {
        __syncthreads();
        *(short8*)stg_dst = *(const short8*)(Wn2T + stg_n * HID + kt * 32 + stg_p * 8);
        __syncthreads();
        short8 a = *(const short8*)(efs + mA * 136 + kt * 32 + quad * 8);
#pragma unroll
        for (int nt = 0; nt < 8; ++nt) {
            short8 b = *(const short8*)(Wc + quad * 1024 + (nt * 16 + l16) * 8);
            acc[nt] = __builtin_amdgcn_mfma_f32_16x16x32_bf16(a, b, acc[nt], 0, 0, 0);
        }
    }

    const int mbase = wave * 16 + quad * 4;
    const int gfirst = batchL[mbase], glast = batchL[min(mbase + 3, 127)];
    const bool same_g = (gfirst == glast) && (n0 + mbase + 3 < N_NODES);
#pragma unroll
    for (int nt = 0; nt < 8; ++nt) {
        int nn = nt * 16 + l16;
        float bias = bn2[nn];
        if (same_g) {
            float s = 0.f;
#pragma unroll
            for (int r = 0; r < 4; ++r) {
                int ndM = n0 + mbase + r;
                s += acc[nt][r] + bias + hf[ndM * HID + nn];
            }
            atomicAdd(&sums[gfirst * HID + nn], s);
        } else {
#pragma unroll
            for (int r = 0; r < 4; ++r) {
                int ndM = n0 + mbase + r;
                if (ndM < N_NODES) {
                    float hn = hf[ndM * HID + nn] + acc[nt][r] + bias;
                    atomicAdd(&sums[batchL[mbase + r] * HID + nn], hn);
                }
            }
        }
    }
}

// Per-graph counts via binary search over sorted batch (no atomics).
__global__ void final_kernel(const float* __restrict__ sums, const int* __restrict__ batch,
                             float* __restrict__ out) {
    __shared__ int cntS[2];
    const int b = blockIdx.x;       // 32 blocks x 2 graphs
    const int tid = threadIdx.x;
    if (tid < 2) {
        int g = b * 2 + tid;
        int lo = 0, hi = N_NODES;
        while (lo < hi) { int mid = (lo + hi) >> 1; if (batch[mid] < g) lo = mid + 1; else hi = mid; }
        int s = lo;
        lo = 0; hi = N_NODES;
        while (lo < hi) { int mid = (lo + hi) >> 1; if (batch[mid] < g + 1) lo = mid + 1; else hi = mid; }
        cntS[tid] = lo - s;
    }
    __syncthreads();
    int i = b * 256 + tid;
    float c = fmaxf((float)cntS[tid >> 7], 1.0f);
    out[i] = sums[i] / c;
}

extern "C" void kernel_launch(void* const* d_in, const int* in_sizes, int n_in,
                              void* d_out, int out_size, void* d_ws, size_t ws_size,
                              hipStream_t stream)
{
    const float* h   = (const float*)d_in[0];
    const int*   ei  = (const int*)d_in[1];
    const float* x   = (const float*)d_in[2];
    const float* ea  = (const float*)d_in[3];
    const int*   bat = (const int*)d_in[4];
    const float* We1 = (const float*)d_in[5];
    const float* be1 = (const float*)d_in[6];
    const float* We2 = (const float*)d_in[7];
    const float* be2 = (const float*)d_in[8];
    const float* Wn1 = (const float*)d_in[9];
    const float* bn1 = (const float*)d_in[10];
    const float* Wn2 = (const float*)d_in[11];
    const float* bn2 = (const float*)d_in[12];

    char* ws = (char*)d_ws;
    unsigned short* We1T = (unsigned short*)(ws + 0);          //    73,728
    unsigned short* We2T = (unsigned short*)(ws + 73728);      //    32,768
    unsigned short* Wn1T = (unsigned short*)(ws + 106496);     //    65,536
    unsigned short* Wn2T = (unsigned short*)(ws + 172032);     //    32,768
    int*   offs_local    = (int*)(ws + 204800);                //   200,000
    int*   chunk_sums    = (int*)(ws + 404800);                //     1,024
    int*   blockpref     = (int*)(ws + 405824);                //     1,024
    unsigned short* srow = (unsigned short*)(ws + 406848);     // 1,600,000
    unsigned short* scol = (unsigned short*)(ws + 2006848);    // 1,600,000
    int*   seid          = (int*)(ws + 3606848);               // 3,200,000
    unsigned short* hb   = (unsigned short*)(ws + 6806848);    // 12,800,000
    // ---- zeroed region (contiguous) ----
    float* sums          = (float*)(ws + 19606848);            //    32,768
    int*   hist          = (int*)(ws + 19639616);              //   200,000
    int*   cursor        = (int*)(ws + 19839616);              //   200,000
    float* agg           = (float*)(ws + 20039616);            // 25,600,000 -> end 45,639,616

    hipMemsetAsync(ws + 19606848, 0, 26032768, stream);

    prep_kernel<<<512, 256, 0, stream>>>(We1, We2, Wn1, Wn2, h, ei,
                                         We1T, We2T, Wn1T, Wn2T, hb, hist);
    scan1_kernel<<<196, 256, 0, stream>>>(hist, offs_local, chunk_sums);
    scan2_kernel<<<1, 256, 0, stream>>>(chunk_sums, blockpref);
    scatter_kernel<<<(N_EDGES + 255) / 256, 256, 0, stream>>>(ei, offs_local, blockpref,
                                                              cursor, srow, scol, seid);
    edge_kernel<<<N_EDGES / 256, 512, 0, stream>>>(hb, srow, scol, seid, x, ea,
                                                   We1T, be1, We2T, be2, agg);
    node_kernel<<<(N_NODES + 127) / 128, 512, 0, stream>>>(hb, h, agg, bat,
                                                           Wn1T, bn1, Wn2T, bn2, sums);
    final_kernel<<<N_GRAPHS / 2, 256, 0, stream>>>(sums, bat, (float*)d_out);
}

// Round 6
// 467.361 us; speedup vs baseline: 1.8395x; 1.0673x over previous
//
#include <hip/hip_runtime.h>

typedef short short8 __attribute__((ext_vector_type(8)));
typedef float f32x4 __attribute__((ext_vector_type(4)));

#define N_NODES  50000
#define N_EDGES  800000
#define HID      128
#define EDGE_D   16
#define N_GRAPHS 64
#define KP1      288   // layer-1 K padded: 128 h_row + 128 h_col + 16 edge_attr + 1 radial + 15 pad

__device__ __forceinline__ float b2f(unsigned short u) {
    union { unsigned int i; float f; } v; v.i = ((unsigned int)u) << 16; return v.f;
}
// round-half-up bf16 conversion: 2 VALU ops (vs 5 for RNE); differs from RNE
// only on exact ties (0.5-ulp max error either way). Finite inputs only.
__device__ __forceinline__ unsigned short f2b(float f) {
    union { unsigned int i; float f; } v; v.f = f;
    return (unsigned short)((v.i + 0x8000u) >> 16);
}
// fast silu: rcp approx (1 ulp) instead of IEEE div (~14 VALU ops -> ~5).
// x->-inf: exp->inf, rcp->0, x*0=0 ok; x->+inf: rcp(1)=1 ok.
__device__ __forceinline__ float silu_f(float x) {
    return x * __builtin_amdgcn_rcpf(1.0f + __expf(-x));
}

__device__ __forceinline__ short8 cvt8(const float* __restrict__ p) {
    float4 f0 = *(const float4*)p;
    float4 f1 = *(const float4*)(p + 4);
    short8 r;
    r[0] = (short)f2b(f0.x); r[1] = (short)f2b(f0.y);
    r[2] = (short)f2b(f0.z); r[3] = (short)f2b(f0.w);
    r[4] = (short)f2b(f1.x); r[5] = (short)f2b(f1.y);
    r[6] = (short)f2b(f1.z); r[7] = (short)f2b(f1.w);
    return r;
}

// ---------------------------------------------------------------------------
// Prep: fp32->bf16 h + weights (transposed [N][K]); row histogram for sort.
// Per-graph counts are computed by binary search in final_kernel (sorted batch;
// 50k same-address atomics on 256B serialized at L2 ~200us — round-4 lesson).
// ---------------------------------------------------------------------------
__global__ void prep_kernel(
    const float* __restrict__ We1, const float* __restrict__ We2,
    const float* __restrict__ Wn1, const float* __restrict__ Wn2,
    const float* __restrict__ h,
    const int* __restrict__ ei,
    unsigned short* __restrict__ We1T, unsigned short* __restrict__ We2T,
    unsigned short* __restrict__ Wn1T, unsigned short* __restrict__ Wn2T,
    unsigned short* __restrict__ h_bf16,
    int* __restrict__ hist)
{
    int stride = gridDim.x * blockDim.x;
    int i0 = blockIdx.x * blockDim.x + threadIdx.x;
    for (int t = i0; t < (N_NODES * HID) / 8; t += stride) {
        *(short8*)(h_bf16 + t * 8) = cvt8(h + t * 8);
    }
    for (int t = i0; t < N_EDGES; t += stride) {
        int r = min(max(ei[t], 0), N_NODES - 1);
        atomicAdd(&hist[r], 1);
    }
    for (int t = i0; t < 128 * KP1; t += stride) {
        int n = t / KP1, kp = t % KP1;
        float v = 0.f;
        int k;
        if (kp < 256) k = kp;
        else if (kp < 272) k = kp + 1;
        else if (kp == 272) k = 256;
        else k = -1;
        if (k >= 0) v = We1[k * HID + n];
        We1T[n * KP1 + kp] = f2b(v);
    }
    for (int t = i0; t < 128 * 128; t += stride) {
        int n = t >> 7, k = t & 127;
        We2T[n * HID + k] = f2b(We2[k * HID + n]);
        Wn2T[n * HID + k] = f2b(Wn2[k * HID + n]);
    }
    for (int t = i0; t < 128 * 256; t += stride) {
        int n = t >> 8, k = t & 255;
        Wn1T[n * 256 + k] = f2b(Wn1[k * HID + n]);
    }
}

// ---------------------------------------------------------------------------
// Two-level exclusive scan of the 50k row histogram (for counting sort).
// ---------------------------------------------------------------------------
__global__ void scan1_kernel(const int* __restrict__ hist, int* __restrict__ offs_local,
                             int* __restrict__ chunk_sums)
{
    __shared__ int buf[256];
    int tid = threadIdx.x, i = blockIdx.x * 256 + tid;
    int v = (i < N_NODES) ? hist[i] : 0;
    buf[tid] = v; __syncthreads();
    for (int off = 1; off < 256; off <<= 1) {
        int t = (tid >= off) ? buf[tid - off] : 0;
        __syncthreads();
        buf[tid] += t;
        __syncthreads();
    }
    if (i < N_NODES) offs_local[i] = buf[tid] - v;
    if (tid == 255) chunk_sums[blockIdx.x] = buf[255];
}

__global__ void scan2_kernel(const int* __restrict__ chunk_sums, int* __restrict__ blockpref)
{
    __shared__ int buf[256];
    int tid = threadIdx.x;
    int v = (tid < 196) ? chunk_sums[tid] : 0;
    buf[tid] = v; __syncthreads();
    for (int off = 1; off < 256; off <<= 1) {
        int t = (tid >= off) ? buf[tid - off] : 0;
        __syncthreads();
        buf[tid] += t;
        __syncthreads();
    }
    if (tid < 196) blockpref[tid] = buf[tid] - v;
}

__global__ void scatter_kernel(const int* __restrict__ ei,
                               const int* __restrict__ offs_local,
                               const int* __restrict__ blockpref,
                               int* __restrict__ cursor,
                               unsigned short* __restrict__ srow,
                               unsigned short* __restrict__ scol,
                               int* __restrict__ seid)
{
    int e = blockIdx.x * 256 + threadIdx.x;
    if (e < N_EDGES) {
        int r = min(max(ei[e], 0), N_NODES - 1);
        int c = min(max(ei[N_EDGES + e], 0), N_NODES - 1);
        int pos = blockpref[r >> 8] + offs_local[r] + atomicAdd(&cursor[r], 1);
        srow[pos] = (unsigned short)r;
        scol[pos] = (unsigned short)c;
        seid[pos] = e;
    }
}

// ---------------------------------------------------------------------------
// Edge MLP over ROW-SORTED edges: 512 thr, 256 edges/block, 2 m-tiles/wave.
// Epilogue: silu -> LDS tile, vectorized block segmented-reduce over equal-row
// runs, float4 stores for interior rows, atomics only at block boundaries.
// ---------------------------------------------------------------------------
__global__ __launch_bounds__(512, 4) void edge_kernel(
    const unsigned short* __restrict__ h,      // bf16
    const unsigned short* __restrict__ srow,
    const unsigned short* __restrict__ scol,
    const int* __restrict__ seid,
    const float* __restrict__ x,
    const float* __restrict__ ea,
    const unsigned short* __restrict__ We1T,
    const float* __restrict__ be1,
    const unsigned short* __restrict__ We2T,
    const float* __restrict__ be2,
    float* __restrict__ agg)
{
    __shared__ unsigned short efs[256 * 136];       // 69,632 B
    __shared__ unsigned short Wc[4 * 128 * 8];      //  8,192 B  [part][n][8]
    __shared__ unsigned short rowS[256];
    __shared__ unsigned short colS[256];
    __shared__ unsigned short radB[256];
    __shared__ unsigned short segS[256];
    __shared__ unsigned short segL[256];
    __shared__ int nsegL;

    const int tid  = threadIdx.x;
    const int wave = tid >> 6;
    const int lane = tid & 63;
    const int quad = lane >> 4;
    const int l16  = lane & 15;
    const int e0   = blockIdx.x * 256;

    if (tid == 0) nsegL = 0;
    if (tid < 256) {
        int e = e0 + tid;
        int r = srow[e];
        int c = scol[e];
        rowS[tid] = (unsigned short)r;
        colS[tid] = (unsigned short)c;
        float dx = x[r * 3 + 0] - x[c * 3 + 0];
        float dy = x[r * 3 + 1] - x[c * 3 + 1];
        float dz = x[r * 3 + 2] - x[c * 3 + 2];
        radB[tid] = f2b(dx * dx + dy * dy + dz * dz);
    }
    __syncthreads();

    // discover equal-row segments (sorted -> contiguous runs)
    if (tid < 256) {
        bool head = (tid == 0) || (rowS[tid] != rowS[tid - 1]);
        if (head) {
            int j = tid + 1;
            while (j < 256 && rowS[j] == rowS[tid]) ++j;
            int s = atomicAdd(&nsegL, 1);
            segS[s] = (unsigned short)tid;
            segL[s] = (unsigned short)(j - tid);
        }
    }

    const int m0 = wave * 32 + l16;
    const int m1 = m0 + 16;
    const int rA0 = rowS[m0], cA0 = colS[m0];
    const int rA1 = rowS[m1], cA1 = colS[m1];

    const int stg_n = tid >> 2, stg_p = tid & 3;
    unsigned short* stg_dst = Wc + stg_p * 1024 + stg_n * 8;

    const f32x4 fz = {0.f, 0.f, 0.f, 0.f};
    f32x4 acc0[8], acc1[8];
#pragma unroll
    for (int i = 0; i < 8; ++i) { acc0[i] = fz; acc1[i] = fz; }

    // ---- layer 1: K = 288 ----
    for (int kt = 0; kt < 9; ++kt) {
        __syncthreads();
        *(short8*)stg_dst = *(const short8*)(We1T + stg_n * KP1 + kt * 32 + stg_p * 8);
        short8 a0, a1;
        if (kt < 4) {
            a0 = *(const short8*)(h + rA0 * HID + kt * 32 + quad * 8);
            a1 = *(const short8*)(h + rA1 * HID + kt * 32 + quad * 8);
        } else if (kt < 8) {
            a0 = *(const short8*)(h + cA0 * HID + (kt - 4) * 32 + quad * 8);
            a1 = *(const short8*)(h + cA1 * HID + (kt - 4) * 32 + quad * 8);
        } else {
            short8 t0 = {0, 0, 0, 0, 0, 0, 0, 0}, t1 = t0;
            if (quad == 0) {
                t0 = cvt8(ea + (long)seid[e0 + m0] * EDGE_D);
                t1 = cvt8(ea + (long)seid[e0 + m1] * EDGE_D);
            } else if (quad == 1) {
                t0 = cvt8(ea + (long)seid[e0 + m0] * EDGE_D + 8);
                t1 = cvt8(ea + (long)seid[e0 + m1] * EDGE_D + 8);
            } else if (quad == 2) {
                t0[0] = (short)radB[m0];
                t1[0] = (short)radB[m1];
            }
            a0 = t0; a1 = t1;
        }
        __syncthreads();
#pragma unroll
        for (int nt = 0; nt < 8; ++nt) {
            short8 b = *(const short8*)(Wc + quad * 1024 + (nt * 16 + l16) * 8);
            acc0[nt] = __builtin_amdgcn_mfma_f32_16x16x32_bf16(a0, b, acc0[nt], 0, 0, 0);
            acc1[nt] = __builtin_amdgcn_mfma_f32_16x16x32_bf16(a1, b, acc1[nt], 0, 0, 0);
        }
    }

    // layer-1 epilogue: bias + silu -> efs (bf16)
#pragma unroll
    for (int nt = 0; nt < 8; ++nt) {
        float bias = be1[nt * 16 + l16];
#pragma unroll
        for (int r = 0; r < 4; ++r) {
            int mm = wave * 32 + quad * 4 + r;
            efs[mm * 136 + nt * 16 + l16]        = f2b(silu_f(acc0[nt][r] + bias));
            efs[(mm + 16) * 136 + nt * 16 + l16] = f2b(silu_f(acc1[nt][r] + bias));
        }
        acc0[nt] = fz; acc1[nt] = fz;
    }

    // ---- layer 2: K = 128 ----
    for (int kt = 0; kt < 4; ++kt) {
        __syncthreads();
        *(short8*)stg_dst = *(const short8*)(We2T + stg_n * HID + kt * 32 + stg_p * 8);
        __syncthreads();
        short8 a0 = *(const short8*)(efs + m0 * 136 + kt * 32 + quad * 8);
        short8 a1 = *(const short8*)(efs + m1 * 136 + kt * 32 + quad * 8);
#pragma unroll
        for (int nt = 0; nt < 8; ++nt) {
            short8 b = *(const short8*)(Wc + quad * 1024 + (nt * 16 + l16) * 8);
            acc0[nt] = __builtin_amdgcn_mfma_f32_16x16x32_bf16(a0, b, acc0[nt], 0, 0, 0);
            acc1[nt] = __builtin_amdgcn_mfma_f32_16x16x32_bf16(a1, b, acc1[nt], 0, 0, 0);
        }
    }

    // layer-2 epilogue: silu -> efs (own wave's rows; reads of efs done above)
#pragma unroll
    for (int nt = 0; nt < 8; ++nt) {
        float bias = be2[nt * 16 + l16];
#pragma unroll
        for (int r = 0; r < 4; ++r) {
            int mm = wave * 32 + quad * 4 + r;
            efs[mm * 136 + nt * 16 + l16]        = f2b(silu_f(acc0[nt][r] + bias));
            efs[(mm + 16) * 136 + nt * 16 + l16] = f2b(silu_f(acc1[nt][r] + bias));
        }
    }
    __syncthreads();

    // vectorized segmented reduce: 32 slots x 16 threads; ds_read_b128 per
    // 8 columns; float4 stores (atomics only at block-boundary rows)
    const int slot = tid >> 4;         // 0..31
    const int sub  = tid & 15;         // columns sub*8 .. sub*8+7
    for (int s = slot; s < nsegL; s += 32) {
        int st = segS[s], ln = segL[s];
        int row = rowS[st];
        f32x4 s0 = fz, s1 = fz;
        for (int i = 0; i < ln; ++i) {
            short8 v = *(const short8*)(efs + (st + i) * 136 + sub * 8);
            s0[0] += b2f((unsigned short)v[0]); s0[1] += b2f((unsigned short)v[1]);
            s0[2] += b2f((unsigned short)v[2]); s0[3] += b2f((unsigned short)v[3]);
            s1[0] += b2f((unsigned short)v[4]); s1[1] += b2f((unsigned short)v[5]);
            s1[2] += b2f((unsigned short)v[6]); s1[3] += b2f((unsigned short)v[7]);
        }
        float* dst = agg + row * HID + sub * 8;
        if (st == 0 || st + ln == 256) {
#pragma unroll
            for (int j = 0; j < 4; ++j) {
                atomicAdd(dst + j, s0[j]);
                atomicAdd(dst + 4 + j, s1[j]);
            }
        } else {
            *(f32x4*)dst = s0;
            *(f32x4*)(dst + 4) = s1;
        }
    }
}

// ---------------------------------------------------------------------------
// Node MLP + residual + fused pooled-sum scatter.
// ---------------------------------------------------------------------------
__global__ __launch_bounds__(512, 4) void node_kernel(
    const unsigned short* __restrict__ hb,
    const float* __restrict__ hf,
    const float* __restrict__ agg,
    const int* __restrict__ batch,
    const unsigned short* __restrict__ Wn1T,
    const float* __restrict__ bn1,
    const unsigned short* __restrict__ Wn2T,
    const float* __restrict__ bn2,
    float* __restrict__ sums)
{
    __shared__ unsigned short efs[128 * 136];
    __shared__ unsigned short Wc[4 * 128 * 8];
    __shared__ int batchL[128];

    const int tid  = threadIdx.x;
    const int wave = tid >> 6;
    const int lane = tid & 63;
    const int quad = lane >> 4;
    const int l16  = lane & 15;
    const int n0   = blockIdx.x * 128;

    if (tid < 128) {
        int nd = n0 + tid;
        int g = (nd < N_NODES) ? batch[nd] : 0;
        batchL[tid] = min(max(g, 0), N_GRAPHS - 1);
    }
    __syncthreads();

    const int mA  = wave * 16 + l16;
    const int ndA = min(n0 + mA, N_NODES - 1);
    const int stg_n = tid >> 2, stg_p = tid & 3;
    unsigned short* stg_dst = Wc + stg_p * 1024 + stg_n * 8;

    const f32x4 fz = {0.f, 0.f, 0.f, 0.f};
    f32x4 acc[8];
#pragma unroll
    for (int i = 0; i < 8; ++i) acc[i] = fz;

    for (int kt = 0; kt < 8; ++kt) {
        __syncthreads();
        *(short8*)stg_dst = *(const short8*)(Wn1T + stg_n * 256 + kt * 32 + stg_p * 8);
        short8 a;
        if (kt < 4) a = *(const short8*)(hb + ndA * HID + kt * 32 + quad * 8);
        else        a = cvt8(agg + ndA * HID + (kt - 4) * 32 + quad * 8);
        __syncthreads();
#pragma unroll
        for (int nt = 0; nt < 8; ++nt) {
            short8 b = *(const short8*)(Wc + quad * 1024 + (nt * 16 + l16) * 8);
            acc[nt] = __builtin_amdgcn_mfma_f32_16x16x32_bf16(a, b, acc[nt], 0, 0, 0);
        }
    }

#pragma unroll
    for (int nt = 0; nt < 8; ++nt) {
        float bias = bn1[nt * 16 + l16];
#pragma unroll
        for (int r = 0; r < 4; ++r) {
            int mm = wave * 16 + quad * 4 + r;
            efs[mm * 136 + nt * 16 + l16] = f2b(silu_f(acc[nt][r] + bias));
        }
        acc[nt] = fz;
    }

    for (int kt = 0; kt < 4; ++kt) {
        __syncthreads();
        *(short8*)stg_dst = *(const short8*)(Wn2T + stg_n * HID + kt * 32 + stg_p * 8);
        __syncthreads();
        short8 a = *(const short8*)(efs + mA * 136 + kt * 32 + quad * 8);
#pragma unroll
        for (int nt = 0; nt < 8; ++nt) {
            short8 b = *(const short8*)(Wc + quad * 1024 + (nt * 16 + l16) * 8);
            acc[nt] = __builtin_amdgcn_mfma_f32_16x16x32_bf16(a, b, acc[nt], 0, 0, 0);
        }
    }

    const int mbase = wave * 16 + quad * 4;
    const int gfirst = batchL[mbase], glast = batchL[min(mbase + 3, 127)];
    const bool same_g = (gfirst == glast) && (n0 + mbase + 3 < N_NODES);
#pragma unroll
    for (int nt = 0; nt < 8; ++nt) {
        int nn = nt * 16 + l16;
        float bias = bn2[nn];
        if (same_g) {
            float s = 0.f;
#pragma unroll
            for (int r = 0; r < 4; ++r) {
                int ndM = n0 + mbase + r;
                s += acc[nt][r] + bias + hf[ndM * HID + nn];
            }
            atomicAdd(&sums[gfirst * HID + nn], s);
        } else {
#pragma unroll
            for (int r = 0; r < 4; ++r) {
                int ndM = n0 + mbase + r;
                if (ndM < N_NODES) {
                    float hn = hf[ndM * HID + nn] + acc[nt][r] + bias;
                    atomicAdd(&sums[batchL[mbase + r] * HID + nn], hn);
                }
            }
        }
    }
}

// Per-graph counts via binary search over sorted batch (no atomics).
__global__ void final_kernel(const float* __restrict__ sums, const int* __restrict__ batch,
                             float* __restrict__ out) {
    __shared__ int cntS[2];
    const int b = blockIdx.x;       // 32 blocks x 2 graphs
    const int tid = threadIdx.x;
    if (tid < 2) {
        int g = b * 2 + tid;
        int lo = 0, hi = N_NODES;
        while (lo < hi) { int mid = (lo + hi) >> 1; if (batch[mid] < g) lo = mid + 1; else hi = mid; }
        int s = lo;
        lo = 0; hi = N_NODES;
        while (lo < hi) { int mid = (lo + hi) >> 1; if (batch[mid] < g + 1) lo = mid + 1; else hi = mid; }
        cntS[tid] = lo - s;
    }
    __syncthreads();
    int i = b * 256 + tid;
    float c = fmaxf((float)cntS[tid >> 7], 1.0f);
    out[i] = sums[i] / c;
}

extern "C" void kernel_launch(void* const* d_in, const int* in_sizes, int n_in,
                              void* d_out, int out_size, void* d_ws, size_t ws_size,
                              hipStream_t stream)
{
    const float* h   = (const float*)d_in[0];
    const int*   ei  = (const int*)d_in[1];
    const float* x   = (const float*)d_in[2];
    const float* ea  = (const float*)d_in[3];
    const int*   bat = (const int*)d_in[4];
    const float* We1 = (const float*)d_in[5];
    const float* be1 = (const float*)d_in[6];
    const float* We2 = (const float*)d_in[7];
    const float* be2 = (const float*)d_in[8];
    const float* Wn1 = (const float*)d_in[9];
    const float* bn1 = (const float*)d_in[10];
    const float* Wn2 = (const float*)d_in[11];
    const float* bn2 = (const float*)d_in[12];

    char* ws = (char*)d_ws;
    unsigned short* We1T = (unsigned short*)(ws + 0);          //    73,728
    unsigned short* We2T = (unsigned short*)(ws + 73728);      //    32,768
    unsigned short* Wn1T = (unsigned short*)(ws + 106496);     //    65,536
    unsigned short* Wn2T = (unsigned short*)(ws + 172032);     //    32,768
    int*   offs_local    = (int*)(ws + 204800);                //   200,000
    int*   chunk_sums    = (int*)(ws + 404800);                //     1,024
    int*   blockpref     = (int*)(ws + 405824);                //     1,024
    unsigned short* srow = (unsigned short*)(ws + 406848);     // 1,600,000
    unsigned short* scol = (unsigned short*)(ws + 2006848);    // 1,600,000
    int*   seid          = (int*)(ws + 3606848);               // 3,200,000
    unsigned short* hb   = (unsigned short*)(ws + 6806848);    // 12,800,000
    // ---- zeroed region (contiguous) ----
    float* sums          = (float*)(ws + 19606848);            //    32,768
    int*   hist          = (int*)(ws + 19639616);              //   200,000
    int*   cursor        = (int*)(ws + 19839616);              //   200,000
    float* agg           = (float*)(ws + 20039616);            // 25,600,000 -> end 45,639,616

    hipMemsetAsync(ws + 19606848, 0, 26032768, stream);

    prep_kernel<<<512, 256, 0, stream>>>(We1, We2, Wn1, Wn2, h, ei,
                                         We1T, We2T, Wn1T, Wn2T, hb, hist);
    scan1_kernel<<<196, 256, 0, stream>>>(hist, offs_local, chunk_sums);
    scan2_kernel<<<1, 256, 0, stream>>>(chunk_sums, blockpref);
    scatter_kernel<<<(N_EDGES + 255) / 256, 256, 0, stream>>>(ei, offs_local, blockpref,
                                                              cursor, srow, scol, seid);
    edge_kernel<<<N_EDGES / 256, 512, 0, stream>>>(hb, srow, scol, seid, x, ea,
                                                   We1T, be1, We2T, be2, agg);
    node_kernel<<<(N_NODES + 127) / 128, 512, 0, stream>>>(hb, h, agg, bat,
                                                           Wn1T, bn1, Wn2T, bn2, sums);
    final_kernel<<<N_GRAPHS / 2, 256, 0, stream>>>(sums, bat, (float*)d_out);
}

// Round 7
// 420.064 us; speedup vs baseline: 2.0466x; 1.1126x over previous
//
#include <hip/hip_runtime.h>

typedef short short8 __attribute__((ext_vector_type(8)));
typedef float f32x4 __attribute__((ext_vector_type(4)));

#define N_NODES  50000
#define N_EDGES  800000
#define HID      128
#define EDGE_D   16
#define N_GRAPHS 64
#define KP1      288   // layer-1 K padded: 128 h_row + 128 h_col + 16 edge_attr + 1 radial + 15 pad

__device__ __forceinline__ float b2f(unsigned short u) {
    union { unsigned int i; float f; } v; v.i = ((unsigned int)u) << 16; return v.f;
}
// round-half-up bf16 conversion: 2 VALU ops (vs 5 for RNE).
__device__ __forceinline__ unsigned short f2b(float f) {
    union { unsigned int i; float f; } v; v.f = f;
    return (unsigned short)((v.i + 0x8000u) >> 16);
}
// fast silu: rcp approx (1 ulp) instead of IEEE div.
__device__ __forceinline__ float silu_f(float x) {
    return x * __builtin_amdgcn_rcpf(1.0f + __expf(-x));
}

__device__ __forceinline__ short8 cvt8(const float* __restrict__ p) {
    float4 f0 = *(const float4*)p;
    float4 f1 = *(const float4*)(p + 4);
    short8 r;
    r[0] = (short)f2b(f0.x); r[1] = (short)f2b(f0.y);
    r[2] = (short)f2b(f0.z); r[3] = (short)f2b(f0.w);
    r[4] = (short)f2b(f1.x); r[5] = (short)f2b(f1.y);
    r[6] = (short)f2b(f1.z); r[7] = (short)f2b(f1.w);
    return r;
}

// ---------------------------------------------------------------------------
// Prep: fp32->bf16 h + weights (transposed [N][K]); row histogram for sort.
// ---------------------------------------------------------------------------
__global__ void prep_kernel(
    const float* __restrict__ We1, const float* __restrict__ We2,
    const float* __restrict__ Wn1, const float* __restrict__ Wn2,
    const float* __restrict__ h,
    const int* __restrict__ ei,
    unsigned short* __restrict__ We1T, unsigned short* __restrict__ We2T,
    unsigned short* __restrict__ Wn1T, unsigned short* __restrict__ Wn2T,
    unsigned short* __restrict__ h_bf16,
    int* __restrict__ hist)
{
    int stride = gridDim.x * blockDim.x;
    int i0 = blockIdx.x * blockDim.x + threadIdx.x;
    for (int t = i0; t < (N_NODES * HID) / 8; t += stride) {
        *(short8*)(h_bf16 + t * 8) = cvt8(h + t * 8);
    }
    for (int t = i0; t < N_EDGES; t += stride) {
        int r = min(max(ei[t], 0), N_NODES - 1);
        atomicAdd(&hist[r], 1);
    }
    for (int t = i0; t < 128 * KP1; t += stride) {
        int n = t / KP1, kp = t % KP1;
        float v = 0.f;
        int k;
        if (kp < 256) k = kp;
        else if (kp < 272) k = kp + 1;
        else if (kp == 272) k = 256;
        else k = -1;
        if (k >= 0) v = We1[k * HID + n];
        We1T[n * KP1 + kp] = f2b(v);
    }
    for (int t = i0; t < 128 * 128; t += stride) {
        int n = t >> 7, k = t & 127;
        We2T[n * HID + k] = f2b(We2[k * HID + n]);
        Wn2T[n * HID + k] = f2b(Wn2[k * HID + n]);
    }
    for (int t = i0; t < 128 * 256; t += stride) {
        int n = t >> 8, k = t & 255;
        Wn1T[n * 256 + k] = f2b(Wn1[k * HID + n]);
    }
}

// ---------------------------------------------------------------------------
// Two-level exclusive scan of the 50k row histogram (for counting sort).
// ---------------------------------------------------------------------------
__global__ void scan1_kernel(const int* __restrict__ hist, int* __restrict__ offs_local,
                             int* __restrict__ chunk_sums)
{
    __shared__ int buf[256];
    int tid = threadIdx.x, i = blockIdx.x * 256 + tid;
    int v = (i < N_NODES) ? hist[i] : 0;
    buf[tid] = v; __syncthreads();
    for (int off = 1; off < 256; off <<= 1) {
        int t = (tid >= off) ? buf[tid - off] : 0;
        __syncthreads();
        buf[tid] += t;
        __syncthreads();
    }
    if (i < N_NODES) offs_local[i] = buf[tid] - v;
    if (tid == 255) chunk_sums[blockIdx.x] = buf[255];
}

__global__ void scan2_kernel(const int* __restrict__ chunk_sums, int* __restrict__ blockpref)
{
    __shared__ int buf[256];
    int tid = threadIdx.x;
    int v = (tid < 196) ? chunk_sums[tid] : 0;
    buf[tid] = v; __syncthreads();
    for (int off = 1; off < 256; off <<= 1) {
        int t = (tid >= off) ? buf[tid - off] : 0;
        __syncthreads();
        buf[tid] += t;
        __syncthreads();
    }
    if (tid < 196) blockpref[tid] = buf[tid] - v;
}

__global__ void scatter_kernel(const int* __restrict__ ei,
                               const int* __restrict__ offs_local,
                               const int* __restrict__ blockpref,
                               int* __restrict__ cursor,
                               unsigned short* __restrict__ srow,
                               unsigned short* __restrict__ scol,
                               int* __restrict__ seid)
{
    int e = blockIdx.x * 256 + threadIdx.x;
    if (e < N_EDGES) {
        int r = min(max(ei[e], 0), N_NODES - 1);
        int c = min(max(ei[N_EDGES + e], 0), N_NODES - 1);
        int pos = blockpref[r >> 8] + offs_local[r] + atomicAdd(&cursor[r], 1);
        srow[pos] = (unsigned short)r;
        scol[pos] = (unsigned short)c;
        seid[pos] = e;
    }
}

// ---------------------------------------------------------------------------
// Edge MLP over ROW-SORTED edges (unchanged from round 6).
// ---------------------------------------------------------------------------
__global__ __launch_bounds__(512, 4) void edge_kernel(
    const unsigned short* __restrict__ h,      // bf16
    const unsigned short* __restrict__ srow,
    const unsigned short* __restrict__ scol,
    const int* __restrict__ seid,
    const float* __restrict__ x,
    const float* __restrict__ ea,
    const unsigned short* __restrict__ We1T,
    const float* __restrict__ be1,
    const unsigned short* __restrict__ We2T,
    const float* __restrict__ be2,
    float* __restrict__ agg)
{
    __shared__ unsigned short efs[256 * 136];       // 69,632 B
    __shared__ unsigned short Wc[4 * 128 * 8];      //  8,192 B  [part][n][8]
    __shared__ unsigned short rowS[256];
    __shared__ unsigned short colS[256];
    __shared__ unsigned short radB[256];
    __shared__ unsigned short segS[256];
    __shared__ unsigned short segL[256];
    __shared__ int nsegL;

    const int tid  = threadIdx.x;
    const int wave = tid >> 6;
    const int lane = tid & 63;
    const int quad = lane >> 4;
    const int l16  = lane & 15;
    const int e0   = blockIdx.x * 256;

    if (tid == 0) nsegL = 0;
    if (tid < 256) {
        int e = e0 + tid;
        int r = srow[e];
        int c = scol[e];
        rowS[tid] = (unsigned short)r;
        colS[tid] = (unsigned short)c;
        float dx = x[r * 3 + 0] - x[c * 3 + 0];
        float dy = x[r * 3 + 1] - x[c * 3 + 1];
        float dz = x[r * 3 + 2] - x[c * 3 + 2];
        radB[tid] = f2b(dx * dx + dy * dy + dz * dz);
    }
    __syncthreads();

    if (tid < 256) {
        bool head = (tid == 0) || (rowS[tid] != rowS[tid - 1]);
        if (head) {
            int j = tid + 1;
            while (j < 256 && rowS[j] == rowS[tid]) ++j;
            int s = atomicAdd(&nsegL, 1);
            segS[s] = (unsigned short)tid;
            segL[s] = (unsigned short)(j - tid);
        }
    }

    const int m0 = wave * 32 + l16;
    const int m1 = m0 + 16;
    const int rA0 = rowS[m0], cA0 = colS[m0];
    const int rA1 = rowS[m1], cA1 = colS[m1];

    const int stg_n = tid >> 2, stg_p = tid & 3;
    unsigned short* stg_dst = Wc + stg_p * 1024 + stg_n * 8;

    const f32x4 fz = {0.f, 0.f, 0.f, 0.f};
    f32x4 acc0[8], acc1[8];
#pragma unroll
    for (int i = 0; i < 8; ++i) { acc0[i] = fz; acc1[i] = fz; }

    // ---- layer 1: K = 288 ----
    for (int kt = 0; kt < 9; ++kt) {
        __syncthreads();
        *(short8*)stg_dst = *(const short8*)(We1T + stg_n * KP1 + kt * 32 + stg_p * 8);
        short8 a0, a1;
        if (kt < 4) {
            a0 = *(const short8*)(h + rA0 * HID + kt * 32 + quad * 8);
            a1 = *(const short8*)(h + rA1 * HID + kt * 32 + quad * 8);
        } else if (kt < 8) {
            a0 = *(const short8*)(h + cA0 * HID + (kt - 4) * 32 + quad * 8);
            a1 = *(const short8*)(h + cA1 * HID + (kt - 4) * 32 + quad * 8);
        } else {
            short8 t0 = {0, 0, 0, 0, 0, 0, 0, 0}, t1 = t0;
            if (quad == 0) {
                t0 = cvt8(ea + (long)seid[e0 + m0] * EDGE_D);
                t1 = cvt8(ea + (long)seid[e0 + m1] * EDGE_D);
            } else if (quad == 1) {
                t0 = cvt8(ea + (long)seid[e0 + m0] * EDGE_D + 8);
                t1 = cvt8(ea + (long)seid[e0 + m1] * EDGE_D + 8);
            } else if (quad == 2) {
                t0[0] = (short)radB[m0];
                t1[0] = (short)radB[m1];
            }
            a0 = t0; a1 = t1;
        }
        __syncthreads();
#pragma unroll
        for (int nt = 0; nt < 8; ++nt) {
            short8 b = *(const short8*)(Wc + quad * 1024 + (nt * 16 + l16) * 8);
            acc0[nt] = __builtin_amdgcn_mfma_f32_16x16x32_bf16(a0, b, acc0[nt], 0, 0, 0);
            acc1[nt] = __builtin_amdgcn_mfma_f32_16x16x32_bf16(a1, b, acc1[nt], 0, 0, 0);
        }
    }

#pragma unroll
    for (int nt = 0; nt < 8; ++nt) {
        float bias = be1[nt * 16 + l16];
#pragma unroll
        for (int r = 0; r < 4; ++r) {
            int mm = wave * 32 + quad * 4 + r;
            efs[mm * 136 + nt * 16 + l16]        = f2b(silu_f(acc0[nt][r] + bias));
            efs[(mm + 16) * 136 + nt * 16 + l16] = f2b(silu_f(acc1[nt][r] + bias));
        }
        acc0[nt] = fz; acc1[nt] = fz;
    }

    // ---- layer 2: K = 128 ----
    for (int kt = 0; kt < 4; ++kt) {
        __syncthreads();
        *(short8*)stg_dst = *(const short8*)(We2T + stg_n * HID + kt * 32 + stg_p * 8);
        __syncthreads();
        short8 a0 = *(const short8*)(efs + m0 * 136 + kt * 32 + quad * 8);
        short8 a1 = *(const short8*)(efs + m1 * 136 + kt * 32 + quad * 8);
#pragma unroll
        for (int nt = 0; nt < 8; ++nt) {
            short8 b = *(const short8*)(Wc + quad * 1024 + (nt * 16 + l16) * 8);
            acc0[nt] = __builtin_amdgcn_mfma_f32_16x16x32_bf16(a0, b, acc0[nt], 0, 0, 0);
            acc1[nt] = __builtin_amdgcn_mfma_f32_16x16x32_bf16(a1, b, acc1[nt], 0, 0, 0);
        }
    }

#pragma unroll
    for (int nt = 0; nt < 8; ++nt) {
        float bias = be2[nt * 16 + l16];
#pragma unroll
        for (int r = 0; r < 4; ++r) {
            int mm = wave * 32 + quad * 4 + r;
            efs[mm * 136 + nt * 16 + l16]        = f2b(silu_f(acc0[nt][r] + bias));
            efs[(mm + 16) * 136 + nt * 16 + l16] = f2b(silu_f(acc1[nt][r] + bias));
        }
    }
    __syncthreads();

    // vectorized segmented reduce: 32 slots x 16 threads
    const int slot = tid >> 4;
    const int sub  = tid & 15;
    for (int s = slot; s < nsegL; s += 32) {
        int st = segS[s], ln = segL[s];
        int row = rowS[st];
        f32x4 s0 = fz, s1 = fz;
        for (int i = 0; i < ln; ++i) {
            short8 v = *(const short8*)(efs + (st + i) * 136 + sub * 8);
            s0[0] += b2f((unsigned short)v[0]); s0[1] += b2f((unsigned short)v[1]);
            s0[2] += b2f((unsigned short)v[2]); s0[3] += b2f((unsigned short)v[3]);
            s1[0] += b2f((unsigned short)v[4]); s1[1] += b2f((unsigned short)v[5]);
            s1[2] += b2f((unsigned short)v[6]); s1[3] += b2f((unsigned short)v[7]);
        }
        float* dst = agg + row * HID + sub * 8;
        if (st == 0 || st + ln == 256) {
#pragma unroll
            for (int j = 0; j < 4; ++j) {
                atomicAdd(dst + j, s0[j]);
                atomicAdd(dst + 4 + j, s1[j]);
            }
        } else {
            *(f32x4*)dst = s0;
            *(f32x4*)(dst + 4) = s1;
        }
    }
}

// ---------------------------------------------------------------------------
// Node MLP + residual + block-reduced pooled-sum. Sorted batch => a 128-node
// block spans <=2 graphs; per-thread partials + LDS tree => 1-2 atomics per
// column per block (was 4096: 1.6M same-sector atomics ~ the hidden 180us).
// ---------------------------------------------------------------------------
__global__ __launch_bounds__(512, 4) void node_kernel(
    const unsigned short* __restrict__ hb,
    const float* __restrict__ hf,
    const float* __restrict__ agg,
    const int* __restrict__ batch,
    const unsigned short* __restrict__ Wn1T,
    const float* __restrict__ bn1,
    const unsigned short* __restrict__ Wn2T,
    const float* __restrict__ bn2,
    float* __restrict__ sums)
{
    __shared__ unsigned short efs[128 * 136];   // reused as float red[32][128] in epilogue
    __shared__ unsigned short Wc[4 * 128 * 8];
    __shared__ int batchL[128];

    const int tid  = threadIdx.x;
    const int wave = tid >> 6;
    const int lane = tid & 63;
    const int quad = lane >> 4;
    const int l16  = lane & 15;
    const int n0   = blockIdx.x * 128;

    if (tid < 128) {
        int nd = min(n0 + tid, N_NODES - 1);
        batchL[tid] = min(max(batch[nd], 0), N_GRAPHS - 1);
    }
    __syncthreads();

    const int mA  = wave * 16 + l16;
    const int ndA = min(n0 + mA, N_NODES - 1);
    const int stg_n = tid >> 2, stg_p = tid & 3;
    unsigned short* stg_dst = Wc + stg_p * 1024 + stg_n * 8;

    const f32x4 fz = {0.f, 0.f, 0.f, 0.f};
    f32x4 acc[8];
#pragma unroll
    for (int i = 0; i < 8; ++i) acc[i] = fz;

    for (int kt = 0; kt < 8; ++kt) {
        __syncthreads();
        *(short8*)stg_dst = *(const short8*)(Wn1T + stg_n * 256 + kt * 32 + stg_p * 8);
        short8 a;
        if (kt < 4) a = *(const short8*)(hb + ndA * HID + kt * 32 + quad * 8);
        else        a = cvt8(agg + ndA * HID + (kt - 4) * 32 + quad * 8);
        __syncthreads();
#pragma unroll
        for (int nt = 0; nt < 8; ++nt) {
            short8 b = *(const short8*)(Wc + quad * 1024 + (nt * 16 + l16) * 8);
            acc[nt] = __builtin_amdgcn_mfma_f32_16x16x32_bf16(a, b, acc[nt], 0, 0, 0);
        }
    }

#pragma unroll
    for (int nt = 0; nt < 8; ++nt) {
        float bias = bn1[nt * 16 + l16];
#pragma unroll
        for (int r = 0; r < 4; ++r) {
            int mm = wave * 16 + quad * 4 + r;
            efs[mm * 136 + nt * 16 + l16] = f2b(silu_f(acc[nt][r] + bias));
        }
        acc[nt] = fz;
    }

    for (int kt = 0; kt < 4; ++kt) {
        __syncthreads();
        *(short8*)stg_dst = *(const short8*)(Wn2T + stg_n * HID + kt * 32 + stg_p * 8);
        __syncthreads();
        short8 a = *(const short8*)(efs + mA * 136 + kt * 32 + quad * 8);
#pragma unroll
        for (int nt = 0; nt < 8; ++nt) {
            short8 b = *(const short8*)(Wc + quad * 1024 + (nt * 16 + l16) * 8);
            acc[nt] = __builtin_amdgcn_mfma_f32_16x16x32_bf16(a, b, acc[nt], 0, 0, 0);
        }
    }

    // ---- epilogue: bias + residual; two-graph block reduction ----
    float bias2[8];
#pragma unroll
    for (int nt = 0; nt < 8; ++nt) bias2[nt] = bn2[nt * 16 + l16];

    const int gA = batchL[0];
    const int gB = batchL[127];
    const int mbase = wave * 16 + quad * 4;
    float sA[8], sB[8];
#pragma unroll
    for (int nt = 0; nt < 8; ++nt) { sA[nt] = 0.f; sB[nt] = 0.f; }
#pragma unroll
    for (int r = 0; r < 4; ++r) {
        int mloc = mbase + r;
        int ndM = n0 + mloc;
        if (ndM < N_NODES) {
            int grp = batchL[mloc];
#pragma unroll
            for (int nt = 0; nt < 8; ++nt) {
                int nn = nt * 16 + l16;
                float hn = hf[ndM * HID + nn] + acc[nt][r] + bias2[nt];
                if (grp == gA)      sA[nt] += hn;
                else if (grp == gB) sB[nt] += hn;
                else atomicAdd(&sums[grp * HID + nn], hn);   // >2 graphs in block: ~never
            }
        }
    }

    __syncthreads();                       // efs reads all done; reuse as red
    float* red = (float*)efs;              // [32][128]
    const int wq = wave * 4 + quad;
#pragma unroll
    for (int nt = 0; nt < 8; ++nt) red[wq * 128 + nt * 16 + l16] = sA[nt];
    __syncthreads();
    if (tid < 128) {
        float s = 0.f;
#pragma unroll
        for (int j = 0; j < 32; ++j) s += red[j * 128 + tid];
        atomicAdd(&sums[gA * HID + tid], s);
    }
    if (gB != gA) {
        __syncthreads();
#pragma unroll
        for (int nt = 0; nt < 8; ++nt) red[wq * 128 + nt * 16 + l16] = sB[nt];
        __syncthreads();
        if (tid < 128) {
            float s = 0.f;
#pragma unroll
            for (int j = 0; j < 32; ++j) s += red[j * 128 + tid];
            atomicAdd(&sums[gB * HID + tid], s);
        }
    }
}

// Per-graph counts via binary search over sorted batch (no atomics).
__global__ void final_kernel(const float* __restrict__ sums, const int* __restrict__ batch,
                             float* __restrict__ out) {
    __shared__ int cntS[2];
    const int b = blockIdx.x;
    const int tid = threadIdx.x;
    if (tid < 2) {
        int g = b * 2 + tid;
        int lo = 0, hi = N_NODES;
        while (lo < hi) { int mid = (lo + hi) >> 1; if (batch[mid] < g) lo = mid + 1; else hi = mid; }
        int s = lo;
        lo = 0; hi = N_NODES;
        while (lo < hi) { int mid = (lo + hi) >> 1; if (batch[mid] < g + 1) lo = mid + 1; else hi = mid; }
        cntS[tid] = lo - s;
    }
    __syncthreads();
    int i = b * 256 + tid;
    float c = fmaxf((float)cntS[tid >> 7], 1.0f);
    out[i] = sums[i] / c;
}

extern "C" void kernel_launch(void* const* d_in, const int* in_sizes, int n_in,
                              void* d_out, int out_size, void* d_ws, size_t ws_size,
                              hipStream_t stream)
{
    const float* h   = (const float*)d_in[0];
    const int*   ei  = (const int*)d_in[1];
    const float* x   = (const float*)d_in[2];
    const float* ea  = (const float*)d_in[3];
    const int*   bat = (const int*)d_in[4];
    const float* We1 = (const float*)d_in[5];
    const float* be1 = (const float*)d_in[6];
    const float* We2 = (const float*)d_in[7];
    const float* be2 = (const float*)d_in[8];
    const float* Wn1 = (const float*)d_in[9];
    const float* bn1 = (const float*)d_in[10];
    const float* Wn2 = (const float*)d_in[11];
    const float* bn2 = (const float*)d_in[12];

    char* ws = (char*)d_ws;
    unsigned short* We1T = (unsigned short*)(ws + 0);          //    73,728
    unsigned short* We2T = (unsigned short*)(ws + 73728);      //    32,768
    unsigned short* Wn1T = (unsigned short*)(ws + 106496);     //    65,536
    unsigned short* Wn2T = (unsigned short*)(ws + 172032);     //    32,768
    int*   offs_local    = (int*)(ws + 204800);                //   200,000
    int*   chunk_sums    = (int*)(ws + 404800);                //     1,024
    int*   blockpref     = (int*)(ws + 405824);                //     1,024
    unsigned short* srow = (unsigned short*)(ws + 406848);     // 1,600,000
    unsigned short* scol = (unsigned short*)(ws + 2006848);    // 1,600,000
    int*   seid          = (int*)(ws + 3606848);               // 3,200,000
    unsigned short* hb   = (unsigned short*)(ws + 6806848);    // 12,800,000
    // ---- zeroed region (contiguous) ----
    float* sums          = (float*)(ws + 19606848);            //    32,768
    int*   hist          = (int*)(ws + 19639616);              //   200,000
    int*   cursor        = (int*)(ws + 19839616);              //   200,000
    float* agg           = (float*)(ws + 20039616);            // 25,600,000 -> end 45,639,616

    hipMemsetAsync(ws + 19606848, 0, 26032768, stream);

    prep_kernel<<<512, 256, 0, stream>>>(We1, We2, Wn1, Wn2, h, ei,
                                         We1T, We2T, Wn1T, Wn2T, hb, hist);
    scan1_kernel<<<196, 256, 0, stream>>>(hist, offs_local, chunk_sums);
    scan2_kernel<<<1, 256, 0, stream>>>(chunk_sums, blockpref);
    scatter_kernel<<<(N_EDGES + 255) / 256, 256, 0, stream>>>(ei, offs_local, blockpref,
                                                              cursor, srow, scol, seid);
    edge_kernel<<<N_EDGES / 256, 512, 0, stream>>>(hb, srow, scol, seid, x, ea,
                                                   We1T, be1, We2T, be2, agg);
    node_kernel<<<(N_NODES + 127) / 128, 512, 0, stream>>>(hb, h, agg, bat,
                                                           Wn1T, bn1, Wn2T, bn2, sums);
    final_kernel<<<N_GRAPHS / 2, 256, 0, stream>>>(sums, bat, (float*)d_out);
}